// Round 1
// baseline (1098.121 us; speedup 1.0000x reference)
//
#include <hip/hip_runtime.h>
#include <hip/hip_fp16.h>

// DSMoE: x(8,2048,512) f32, gate_w(512,4), w1(4,512,2048), w2(4,2048,512)
// out = [ (8,2048,512) f32 ; router_sparse (16384,4) f32 ]
// Sparse top-2 dispatch, fp16 MFMA compute, fp32 accum. ws use ~68.2 MB.

#define NTOK  16384
#define CDIM  512
#define FF    2048
#define NEXP  4
#define FFC   512      // ff chunk width (H ws = CAP*FFC fp16 = 34 MB)
#define NQ    4        // FF / FFC
#define CAP   33280    // 32768 + 4*128 padding headroom
#define BM    128
#define BN    128
#define BK    64

typedef _Float16 f16;
typedef __attribute__((ext_vector_type(8))) _Float16 f16x8;
typedef __attribute__((ext_vector_type(4))) float f32x4;

__device__ __forceinline__ void gload16(const void* g, void* l) {
  __builtin_amdgcn_global_load_lds(
      (const __attribute__((address_space(1))) unsigned int*)g,
      (__attribute__((address_space(3))) unsigned int*)l, 16, 0, 0);
}

__device__ __forceinline__ float gelu_erf(float v) {
  return 0.5f * v * (1.0f + erff(v * 0.70710678118654752440f));
}

// ---------------- small utility kernels ----------------

__global__ __launch_bounds__(256) void k_zero(float4* p, int n) {
  int i = blockIdx.x * 256 + threadIdx.x;
  if (i < n) p[i] = make_float4(0.f, 0.f, 0.f, 0.f);
}

__global__ __launch_bounds__(256) void k_init(int* list, float* wgt, int* cnt) {
  int i = blockIdx.x * 256 + threadIdx.x;
  if (i < CAP) { list[i] = -1; wgt[i] = 0.f; }
  if (i < 4) cnt[i] = 0;
}

__global__ __launch_bounds__(256) void k_cast_x(const float* __restrict__ x,
                                                f16* __restrict__ xh) {
  int i = (blockIdx.x * 256 + threadIdx.x) * 8;
  float4 a = *(const float4*)(x + i);
  float4 b = *(const float4*)(x + i + 4);
  union { f16 h[8]; uint4 u; } pk;
  pk.h[0] = (f16)a.x; pk.h[1] = (f16)a.y; pk.h[2] = (f16)a.z; pk.h[3] = (f16)a.w;
  pk.h[4] = (f16)b.x; pk.h[5] = (f16)b.y; pk.h[6] = (f16)b.z; pk.h[7] = (f16)b.w;
  *(uint4*)(xh + i) = pk.u;
}

// transpose-cast: in [E][R][Cc] f32 -> out [E][Cc][R] f16, 64x64 tiles
__global__ __launch_bounds__(256) void k_cast_t(const float* __restrict__ in,
                                                f16* __restrict__ out, int R, int Cc) {
  __shared__ f16 T[64][72];   // 72*2=144B row stride (16B multiple, conflict-light)
  int ez = blockIdx.z;
  const float* ine = in + (size_t)ez * R * Cc;
  f16* oute = out + (size_t)ez * R * Cc;
  int c0 = blockIdx.x * 64;
  int r0 = blockIdx.y * 64;
  int t = threadIdx.x;
  {
    int rr = t >> 2, cc = (t & 3) * 16;
    const float* src = ine + (size_t)(r0 + rr) * Cc + c0 + cc;
    union { f16 h[16]; uint4 u[2]; } pk;
#pragma unroll
    for (int j = 0; j < 16; j += 4) {
      float4 a = *(const float4*)(src + j);
      pk.h[j] = (f16)a.x; pk.h[j + 1] = (f16)a.y;
      pk.h[j + 2] = (f16)a.z; pk.h[j + 3] = (f16)a.w;
    }
    *(uint4*)&T[rr][cc] = pk.u[0];
    *(uint4*)&T[rr][cc + 8] = pk.u[1];
  }
  __syncthreads();
  {
    int oc = t >> 2, orr = (t & 3) * 16;
    union { f16 h[16]; uint4 u[2]; } pk;
#pragma unroll
    for (int j = 0; j < 16; ++j) pk.h[j] = T[orr + j][oc];
    f16* dst = oute + (size_t)(c0 + oc) * R + r0 + orr;
    *(uint4*)dst = pk.u[0];
    *(uint4*)(dst + 8) = pk.u[1];
  }
}

// ---------------- router (fp32 exact) ----------------

__global__ __launch_bounds__(256) void k_router(const float* __restrict__ x,
                                                const float* __restrict__ gw,
                                                float* __restrict__ rout,
                                                float4* __restrict__ tokinfo,
                                                int* __restrict__ cnt) {
  int t = blockIdx.x * 256 + threadIdx.x;
  int tok = t >> 6, lane = t & 63;
  if (tok >= NTOK) return;
  const float4* xr = (const float4*)(x + (size_t)tok * CDIM + lane * 8);
  float4 a0 = xr[0], a1 = xr[1];
  float xv[8] = {a0.x, a0.y, a0.z, a0.w, a1.x, a1.y, a1.z, a1.w};
  const float4* g = ((const float4*)gw) + lane * 8;
  float l0 = 0, l1 = 0, l2 = 0, l3 = 0;
#pragma unroll
  for (int j = 0; j < 8; ++j) {
    float4 gv = g[j];
    l0 = fmaf(xv[j], gv.x, l0); l1 = fmaf(xv[j], gv.y, l1);
    l2 = fmaf(xv[j], gv.z, l2); l3 = fmaf(xv[j], gv.w, l3);
  }
#pragma unroll
  for (int off = 32; off; off >>= 1) {
    l0 += __shfl_xor(l0, off); l1 += __shfl_xor(l1, off);
    l2 += __shfl_xor(l2, off); l3 += __shfl_xor(l3, off);
  }
  if (lane == 0) {
    float lg[4] = {l0, l1, l2, l3};
    float m = fmaxf(fmaxf(lg[0], lg[1]), fmaxf(lg[2], lg[3]));
    float p[4], s = 0.f;
#pragma unroll
    for (int e = 0; e < 4; ++e) { p[e] = expf(lg[e] - m); s += p[e]; }
    int i0 = 0;
#pragma unroll
    for (int e = 1; e < 4; ++e) if (lg[e] > lg[i0]) i0 = e;   // ties -> lower idx
    int i1 = -1;
#pragma unroll
    for (int e = 0; e < 4; ++e)
      if (e != i0 && (i1 < 0 || lg[e] > lg[i1])) i1 = e;
    float p0 = p[i0] / s, p1 = p[i1] / s;
    float ss = fmaxf(p0 + p1, 1e-6f);
    float w0 = p0 / ss, w1v = p1 / ss;
    float r[4] = {0.f, 0.f, 0.f, 0.f};
    r[i0] = w0; r[i1] = w1v;
    *(float4*)(rout + tok * 4) = make_float4(r[0], r[1], r[2], r[3]);
    float4 ti;
    ti.x = __int_as_float(i0); ti.y = __int_as_float(i1); ti.z = w0; ti.w = w1v;
    tokinfo[tok] = ti;
    atomicAdd(cnt + i0, 1);
    atomicAdd(cnt + i1, 1);
  }
}

__global__ void k_bases(const int* __restrict__ cnt, int* __restrict__ base,
                        int* __restrict__ cursor) {
  if (threadIdx.x == 0 && blockIdx.x == 0) {
    int b = 0;
#pragma unroll
    for (int e = 0; e < 4; ++e) {
      base[e] = b; cursor[e] = b;
      b += (cnt[e] + 127) & ~127;     // 128-aligned regions: blocks never span experts
    }
    base[4] = b;
  }
}

__global__ __launch_bounds__(256) void k_assign(const float4* __restrict__ tokinfo,
                                                int* cursor, int* __restrict__ list,
                                                float* __restrict__ wgt) {
  int n = blockIdx.x * 256 + threadIdx.x;
  if (n >= NTOK) return;
  float4 ti = tokinfo[n];
  int s0 = atomicAdd(cursor + __float_as_int(ti.x), 1);
  list[s0] = n; wgt[s0] = ti.z;
  int s1 = atomicAdd(cursor + __float_as_int(ti.y), 1);
  list[s1] = n; wgt[s1] = ti.w;
}

// ---------------- pass 1: H[slot, ffchunk] = gelu(x[list] @ W1e) ----------------
// 128x128 tile, 4 waves (64x64 each), BK=64, gload_lds w16, XOR-swizzled LDS.

__global__ __launch_bounds__(256) void k_gemm1(const f16* __restrict__ xh,
                                               const f16* __restrict__ w1t, // [E][FF][C]
                                               const int* __restrict__ list,
                                               const int* __restrict__ base,
                                               f16* __restrict__ H, int hq) {
  __shared__ __align__(16) char smem[32768 + 512];
  int* slist = (int*)(smem + 32768);
  int tid = threadIdx.x;
  int m0 = blockIdx.x * BM;
  int h0 = hq + blockIdx.y * BN;
  int e = 0;
#pragma unroll
  for (int i = 1; i < 4; ++i) if (m0 >= base[i]) e = i;
  if (tid < BM) {
    int v = list[m0 + tid];
    slist[tid] = v < 0 ? 0 : v;   // clamp pads -> finite garbage, discarded later
  }
  __syncthreads();

  int tokr[4];
#pragma unroll
  for (int i = 0; i < 4; ++i) tokr[i] = slist[i * 32 + (tid >> 3)];

  const f16* wB = w1t + (size_t)(e * FF + h0) * CDIM;
  int kbs = ((tid & 7) * 16) ^ (((tid >> 3) & 7) << 4);  // swizzled src byte-in-row

  f32x4 acc[4][4] = {};
  int lane = tid & 63, w = tid >> 6, wr = w >> 1, wc = w & 1;

  auto stage = [&](int kk) {
#pragma unroll
    for (int i = 0; i < 4; ++i) {   // A: x rows (gathered)
      int L = i * 4096 + tid * 16;
      gload16(xh + (size_t)tokr[i] * CDIM + kk * BK + (kbs >> 1), smem + L);
    }
#pragma unroll
    for (int i = 0; i < 4; ++i) {   // B: w1t rows (h-cols)
      int L = i * 4096 + tid * 16;
      int row = i * 32 + (tid >> 3);
      gload16(wB + (size_t)row * CDIM + kk * BK + (kbs >> 1), smem + 16384 + L);
    }
  };

  auto compute = [&]() {
#pragma unroll
    for (int ks = 0; ks < 2; ++ks) {
      f16x8 af[4], bfr[4];
      int kb = ks * 64 + (lane >> 4) * 16;
#pragma unroll
      for (int fr = 0; fr < 4; ++fr) {
        int row = wr * 64 + fr * 16 + (lane & 15);
        af[fr] = *(const f16x8*)(smem + row * 128 + (kb ^ ((row & 7) << 4)));
      }
#pragma unroll
      for (int fc = 0; fc < 4; ++fc) {
        int col = wc * 64 + fc * 16 + (lane & 15);
        bfr[fc] = *(const f16x8*)(smem + 16384 + col * 128 + (kb ^ ((col & 7) << 4)));
      }
#pragma unroll
      for (int fr = 0; fr < 4; ++fr)
#pragma unroll
        for (int fc = 0; fc < 4; ++fc)
          acc[fr][fc] = __builtin_amdgcn_mfma_f32_16x16x32_f16(af[fr], bfr[fc],
                                                               acc[fr][fc], 0, 0, 0);
    }
  };

  stage(0);
  for (int kk = 0; kk < 8; ++kk) {
    __syncthreads();           // drains vmcnt: staged tile visible
    compute();
    __syncthreads();           // all reads done before restage
    if (kk < 7) stage(kk + 1);
  }

  // epilogue: gelu -> fp16, repack via LDS for coalesced 16B stores
#pragma unroll
  for (int fr = 0; fr < 4; ++fr)
#pragma unroll
    for (int fc = 0; fc < 4; ++fc)
#pragma unroll
      for (int i = 0; i < 4; ++i) {
        int row = wr * 64 + fr * 16 + (lane >> 4) * 4 + i;
        int col = wc * 64 + fc * 16 + (lane & 15);
        float v = gelu_erf(acc[fr][fc][i]);
        int off = (row * 256 + col * 2) ^ ((row & 7) << 4);
        *(f16*)(smem + off) = (f16)v;
      }
  __syncthreads();
  int colb = ((tid & 15) * 16) ^ (((tid >> 4) & 7) << 4);
#pragma unroll
  for (int j = 0; j < 8; ++j) {
    int L = j * 4096 + tid * 16;
    int row = j * 16 + (tid >> 4);
    uint4 v = *(const uint4*)(smem + row * 256 + colb);
    *(uint4*)((char*)H + ((size_t)(m0 + row) * FFC + (h0 - hq)) * 2 + (L & 255)) = v;
  }
}

// ---------------- pass 2: out[list[slot]] += wgt[slot] * (H[slot] @ W2e) ----------------

__global__ __launch_bounds__(256) void k_gemm2(const f16* __restrict__ H,
                                               const f16* __restrict__ w2t, // [E][C][FF]
                                               const int* __restrict__ list,
                                               const float* __restrict__ wgt,
                                               const int* __restrict__ base,
                                               float* __restrict__ out, int hq) {
  __shared__ __align__(16) char smem[32768 + 1024];
  int* slist = (int*)(smem + 32768);
  float* swgt = (float*)(smem + 32768 + 512);
  int tid = threadIdx.x;
  int m0 = blockIdx.x * BM;
  int c0 = blockIdx.y * BN;
  int e = 0;
#pragma unroll
  for (int i = 1; i < 4; ++i) if (m0 >= base[i]) e = i;
  if (tid < BM) {
    slist[tid] = list[m0 + tid];
    swgt[tid] = wgt[m0 + tid];
  }
  __syncthreads();

  const f16* pA = H + (size_t)m0 * FFC;
  const f16* wB = w2t + (size_t)(e * CDIM + c0) * FF + hq;
  int kbs = ((tid & 7) * 16) ^ (((tid >> 3) & 7) << 4);

  f32x4 acc[4][4] = {};
  int lane = tid & 63, w = tid >> 6, wr = w >> 1, wc = w & 1;

  auto stage = [&](int kk) {
#pragma unroll
    for (int i = 0; i < 4; ++i) {   // A: H rows (slots, direct)
      int L = i * 4096 + tid * 16;
      int row = i * 32 + (tid >> 3);
      gload16(pA + (size_t)row * FFC + kk * BK + (kbs >> 1), smem + L);
    }
#pragma unroll
    for (int i = 0; i < 4; ++i) {   // B: w2t rows (out-cols)
      int L = i * 4096 + tid * 16;
      int row = i * 32 + (tid >> 3);
      gload16(wB + (size_t)row * FF + kk * BK + (kbs >> 1), smem + 16384 + L);
    }
  };

  auto compute = [&]() {
#pragma unroll
    for (int ks = 0; ks < 2; ++ks) {
      f16x8 af[4], bfr[4];
      int kb = ks * 64 + (lane >> 4) * 16;
#pragma unroll
      for (int fr = 0; fr < 4; ++fr) {
        int row = wr * 64 + fr * 16 + (lane & 15);
        af[fr] = *(const f16x8*)(smem + row * 128 + (kb ^ ((row & 7) << 4)));
      }
#pragma unroll
      for (int fc = 0; fc < 4; ++fc) {
        int col = wc * 64 + fc * 16 + (lane & 15);
        bfr[fc] = *(const f16x8*)(smem + 16384 + col * 128 + (kb ^ ((col & 7) << 4)));
      }
#pragma unroll
      for (int fr = 0; fr < 4; ++fr)
#pragma unroll
        for (int fc = 0; fc < 4; ++fc)
          acc[fr][fc] = __builtin_amdgcn_mfma_f32_16x16x32_f16(af[fr], bfr[fc],
                                                               acc[fr][fc], 0, 0, 0);
    }
  };

  stage(0);
  for (int kk = 0; kk < 8; ++kk) {
    __syncthreads();
    compute();
    __syncthreads();
    if (kk < 7) stage(kk + 1);
  }

  // epilogue: weight & scatter-add (exactly 2 adds/elem/chunk -> commutative-exact)
#pragma unroll
  for (int fr = 0; fr < 4; ++fr) {
#pragma unroll
    for (int i = 0; i < 4; ++i) {
      int r = wr * 64 + fr * 16 + (lane >> 4) * 4 + i;
      int tok = slist[r];
      if (tok < 0) continue;
      float wv = swgt[r];
      float* orow = out + (size_t)tok * CDIM + c0 + wc * 64 + (lane & 15);
#pragma unroll
      for (int fc = 0; fc < 4; ++fc)
        atomicAdd(orow + fc * 16, acc[fr][fc][i] * wv);
    }
  }
}

// ---------------- host ----------------

extern "C" void kernel_launch(void* const* d_in, const int* in_sizes, int n_in,
                              void* d_out, int out_size, void* d_ws, size_t ws_size,
                              hipStream_t stream) {
  const float* x  = (const float*)d_in[0];
  const float* gw = (const float*)d_in[1];
  const float* w1 = (const float*)d_in[2];
  const float* w2 = (const float*)d_in[3];
  float* out  = (float*)d_out;
  float* rout = out + (size_t)NTOK * CDIM;

  char* ws = (char*)d_ws;
  f16* xh      = (f16*)ws;     ws += (size_t)NTOK * CDIM * 2;      // 16.78 MB
  f16* w1t     = (f16*)ws;     ws += (size_t)NEXP * FF * CDIM * 2; //  8.39 MB
  f16* w2t     = (f16*)ws;     ws += (size_t)NEXP * FF * CDIM * 2; //  8.39 MB
  f16* Hbuf    = (f16*)ws;     ws += (size_t)CAP * FFC * 2;        // 34.08 MB
  float4* tokinfo = (float4*)ws; ws += (size_t)NTOK * 16;          //  0.26 MB
  int* list    = (int*)ws;     ws += (size_t)CAP * 4;
  float* wgt   = (float*)ws;   ws += (size_t)CAP * 4;
  int* cnt     = (int*)ws;     ws += 64;
  int* base    = (int*)ws;     ws += 64;
  int* cursor  = (int*)ws;     ws += 64;

  k_zero<<<8192, 256, 0, stream>>>((float4*)out, NTOK * CDIM / 4);
  k_init<<<(CAP + 255) / 256, 256, 0, stream>>>(list, wgt, cnt);
  k_cast_x<<<NTOK * CDIM / (256 * 8), 256, 0, stream>>>(x, xh);
  k_cast_t<<<dim3(FF / 64, CDIM / 64, NEXP), 256, 0, stream>>>(w1, w1t, CDIM, FF);
  k_cast_t<<<dim3(CDIM / 64, FF / 64, NEXP), 256, 0, stream>>>(w2, w2t, FF, CDIM);
  k_router<<<NTOK / 4, 256, 0, stream>>>(x, gw, rout, tokinfo, cnt);
  k_bases<<<1, 64, 0, stream>>>(cnt, base, cursor);
  k_assign<<<NTOK / 256, 256, 0, stream>>>(tokinfo, cursor, list, wgt);

  for (int q = 0; q < NQ; ++q) {
    k_gemm1<<<dim3(CAP / BM, FFC / BN), 256, 0, stream>>>(xh, w1t, list, base,
                                                          Hbuf, q * FFC);
    k_gemm2<<<dim3(CAP / BM, CDIM / BN), 256, 0, stream>>>(Hbuf, w2t, list, wgt,
                                                           base, out, q * FFC);
  }
}

// Round 2
// 562.901 us; speedup vs baseline: 1.9508x; 1.9508x over previous
//
#include <hip/hip_runtime.h>
#include <hip/hip_fp16.h>

// DSMoE: x(8,2048,512) f32, gate_w(512,4), w1(4,512,2048), w2(4,2048,512)
// out = [ (8,2048,512) f32 ; router_sparse (16384,4) f32 ]
// Sparse top-2 dispatch, fp16 MFMA compute, fp32 accum. ws use ~68.2 MB.
// R2: LDS-aggregated routing atomics (R1: 32768 same-line global atomics = 376us),
//     cast_x fused into router, counters cache-line padded.

#define NTOK  16384
#define CDIM  512
#define FF    2048
#define NEXP  4
#define FFC   512      // ff chunk width (H ws = CAP*FFC fp16 = 34 MB)
#define NQ    4        // FF / FFC
#define CAP   33280    // 32768 + 4*128 padding headroom
#define BM    128
#define BN    128
#define BK    64
#define CPAD  32       // ints per counter line (128B)

typedef _Float16 f16;
typedef __attribute__((ext_vector_type(8))) _Float16 f16x8;
typedef __attribute__((ext_vector_type(4))) float f32x4;

__device__ __forceinline__ void gload16(const void* g, void* l) {
  __builtin_amdgcn_global_load_lds(
      (const __attribute__((address_space(1))) unsigned int*)g,
      (__attribute__((address_space(3))) unsigned int*)l, 16, 0, 0);
}

__device__ __forceinline__ float gelu_erf(float v) {
  return 0.5f * v * (1.0f + erff(v * 0.70710678118654752440f));
}

// ---------------- small utility kernels ----------------

__global__ __launch_bounds__(256) void k_zero(float4* p, int n) {
  int i = blockIdx.x * 256 + threadIdx.x;
  if (i < n) p[i] = make_float4(0.f, 0.f, 0.f, 0.f);
}

__global__ __launch_bounds__(256) void k_init(int* list, float* wgt, int* cnt) {
  int i = blockIdx.x * 256 + threadIdx.x;
  if (i < CAP) { list[i] = -1; wgt[i] = 0.f; }
  if (i < 4) cnt[i * CPAD] = 0;
}

// transpose-cast: in [E][R][Cc] f32 -> out [E][Cc][R] f16, 64x64 tiles
__global__ __launch_bounds__(256) void k_cast_t(const float* __restrict__ in,
                                                f16* __restrict__ out, int R, int Cc) {
  __shared__ f16 T[64][72];
  int ez = blockIdx.z;
  const float* ine = in + (size_t)ez * R * Cc;
  f16* oute = out + (size_t)ez * R * Cc;
  int c0 = blockIdx.x * 64;
  int r0 = blockIdx.y * 64;
  int t = threadIdx.x;
  {
    int rr = t >> 2, cc = (t & 3) * 16;
    const float* src = ine + (size_t)(r0 + rr) * Cc + c0 + cc;
    union { f16 h[16]; uint4 u[2]; } pk;
#pragma unroll
    for (int j = 0; j < 16; j += 4) {
      float4 a = *(const float4*)(src + j);
      pk.h[j] = (f16)a.x; pk.h[j + 1] = (f16)a.y;
      pk.h[j + 2] = (f16)a.z; pk.h[j + 3] = (f16)a.w;
    }
    *(uint4*)&T[rr][cc] = pk.u[0];
    *(uint4*)&T[rr][cc + 8] = pk.u[1];
  }
  __syncthreads();
  {
    int oc = t >> 2, orr = (t & 3) * 16;
    union { f16 h[16]; uint4 u[2]; } pk;
#pragma unroll
    for (int j = 0; j < 16; ++j) pk.h[j] = T[orr + j][oc];
    f16* dst = oute + (size_t)(c0 + oc) * R + r0 + orr;
    *(uint4*)dst = pk.u[0];
    *(uint4*)(dst + 8) = pk.u[1];
  }
}

// ---------------- router (fp32 exact) + fused x->fp16 cast ----------------
// 256 blocks x 64 tokens; wave-per-token over 16 tokens/wave; LDS-agg counts.

__global__ __launch_bounds__(256) void k_router(const float* __restrict__ x,
                                                const float* __restrict__ gw,
                                                f16* __restrict__ xh,
                                                float* __restrict__ rout,
                                                float4* __restrict__ tokinfo,
                                                int* __restrict__ cnt) {
  __shared__ int lcnt[4];
  int tid = threadIdx.x;
  if (tid < 4) lcnt[tid] = 0;
  __syncthreads();
  int wv = tid >> 6, lane = tid & 63;
  const float4* g = ((const float4*)gw) + lane * 8;
  float4 gv[8];
#pragma unroll
  for (int j = 0; j < 8; ++j) gv[j] = g[j];   // gw held in regs for all 16 tokens

  int tok0 = blockIdx.x * 64 + wv * 16;
  for (int i = 0; i < 16; ++i) {
    int tok = tok0 + i;
    const float4* xr = (const float4*)(x + (size_t)tok * CDIM + lane * 8);
    float4 a0 = xr[0], a1 = xr[1];
    union { f16 h[8]; uint4 u; } pk;
    pk.h[0] = (f16)a0.x; pk.h[1] = (f16)a0.y; pk.h[2] = (f16)a0.z; pk.h[3] = (f16)a0.w;
    pk.h[4] = (f16)a1.x; pk.h[5] = (f16)a1.y; pk.h[6] = (f16)a1.z; pk.h[7] = (f16)a1.w;
    *(uint4*)(xh + (size_t)tok * CDIM + lane * 8) = pk.u;
    float xv[8] = {a0.x, a0.y, a0.z, a0.w, a1.x, a1.y, a1.z, a1.w};
    float l0 = 0, l1 = 0, l2 = 0, l3 = 0;
#pragma unroll
    for (int j = 0; j < 8; ++j) {
      float4 g4 = gv[j];
      l0 = fmaf(xv[j], g4.x, l0); l1 = fmaf(xv[j], g4.y, l1);
      l2 = fmaf(xv[j], g4.z, l2); l3 = fmaf(xv[j], g4.w, l3);
    }
#pragma unroll
    for (int off = 32; off; off >>= 1) {
      l0 += __shfl_xor(l0, off); l1 += __shfl_xor(l1, off);
      l2 += __shfl_xor(l2, off); l3 += __shfl_xor(l3, off);
    }
    if (lane == 0) {
      float lg[4] = {l0, l1, l2, l3};
      float m = fmaxf(fmaxf(lg[0], lg[1]), fmaxf(lg[2], lg[3]));
      float p[4], s = 0.f;
#pragma unroll
      for (int e = 0; e < 4; ++e) { p[e] = expf(lg[e] - m); s += p[e]; }
      int i0 = 0;
#pragma unroll
      for (int e = 1; e < 4; ++e) if (lg[e] > lg[i0]) i0 = e;   // ties -> lower idx
      int i1 = -1;
#pragma unroll
      for (int e = 0; e < 4; ++e)
        if (e != i0 && (i1 < 0 || lg[e] > lg[i1])) i1 = e;
      float p0 = p[i0] / s, p1 = p[i1] / s;
      float ss = fmaxf(p0 + p1, 1e-6f);
      float w0 = p0 / ss, w1v = p1 / ss;
      float r[4] = {0.f, 0.f, 0.f, 0.f};
      r[i0] = w0; r[i1] = w1v;
      *(float4*)(rout + tok * 4) = make_float4(r[0], r[1], r[2], r[3]);
      float4 ti;
      ti.x = __int_as_float(i0); ti.y = __int_as_float(i1); ti.z = w0; ti.w = w1v;
      tokinfo[tok] = ti;
      atomicAdd(&lcnt[i0], 1);
      atomicAdd(&lcnt[i1], 1);
    }
  }
  __syncthreads();
  if (tid < 4) atomicAdd(cnt + tid * CPAD, lcnt[tid]);   // 4 padded lines, 256 each
}

__global__ void k_bases(const int* __restrict__ cnt, int* __restrict__ base,
                        int* __restrict__ cursor) {
  if (threadIdx.x == 0 && blockIdx.x == 0) {
    int b = 0;
#pragma unroll
    for (int e = 0; e < 4; ++e) {
      base[e] = b; cursor[e * CPAD] = b;
      b += (cnt[e * CPAD] + 127) & ~127;   // 128-aligned regions
    }
    base[4] = b;
  }
}

// block-aggregated slot assignment: 16 blocks x 1024 tokens, LDS offsets,
// one global atomic per expert per block.
__global__ __launch_bounds__(256) void k_assign(const float4* __restrict__ tokinfo,
                                                int* cursor, int* __restrict__ list,
                                                float* __restrict__ wgt) {
  __shared__ int lcnt[4], lbase[4];
  int tid = threadIdx.x;
  if (tid < 4) lcnt[tid] = 0;
  __syncthreads();
  int t0 = blockIdx.x * 1024 + tid * 4;
  float4 ti[4]; int lo0[4], lo1[4];
#pragma unroll
  for (int j = 0; j < 4; ++j) {
    ti[j] = tokinfo[t0 + j];
    lo0[j] = atomicAdd(&lcnt[__float_as_int(ti[j].x)], 1);
    lo1[j] = atomicAdd(&lcnt[__float_as_int(ti[j].y)], 1);
  }
  __syncthreads();
  if (tid < 4) lbase[tid] = atomicAdd(cursor + tid * CPAD, lcnt[tid]);
  __syncthreads();
#pragma unroll
  for (int j = 0; j < 4; ++j) {
    int s0 = lbase[__float_as_int(ti[j].x)] + lo0[j];
    list[s0] = t0 + j; wgt[s0] = ti[j].z;
    int s1 = lbase[__float_as_int(ti[j].y)] + lo1[j];
    list[s1] = t0 + j; wgt[s1] = ti[j].w;
  }
}

// ---------------- pass 1: H[slot, ffchunk] = gelu(x[list] @ W1e) ----------------
// 128x128 tile, 4 waves (64x64 each), BK=64, gload_lds w16, XOR-swizzled LDS.

__global__ __launch_bounds__(256) void k_gemm1(const f16* __restrict__ xh,
                                               const f16* __restrict__ w1t, // [E][FF][C]
                                               const int* __restrict__ list,
                                               const int* __restrict__ base,
                                               f16* __restrict__ H, int hq) {
  __shared__ __align__(16) char smem[32768 + 512];
  int* slist = (int*)(smem + 32768);
  int tid = threadIdx.x;
  int m0 = blockIdx.x * BM;
  int h0 = hq + blockIdx.y * BN;
  int e = 0;
#pragma unroll
  for (int i = 1; i < 4; ++i) if (m0 >= base[i]) e = i;
  if (tid < BM) {
    int v = list[m0 + tid];
    slist[tid] = v < 0 ? 0 : v;   // clamp pads -> finite garbage, discarded later
  }
  __syncthreads();

  int tokr[4];
#pragma unroll
  for (int i = 0; i < 4; ++i) tokr[i] = slist[i * 32 + (tid >> 3)];

  const f16* wB = w1t + (size_t)(e * FF + h0) * CDIM;
  int kbs = ((tid & 7) * 16) ^ (((tid >> 3) & 7) << 4);  // swizzled src byte-in-row

  f32x4 acc[4][4] = {};
  int lane = tid & 63, w = tid >> 6, wr = w >> 1, wc = w & 1;

  auto stage = [&](int kk) {
#pragma unroll
    for (int i = 0; i < 4; ++i) {   // A: x rows (gathered)
      int L = i * 4096 + tid * 16;
      gload16(xh + (size_t)tokr[i] * CDIM + kk * BK + (kbs >> 1), smem + L);
    }
#pragma unroll
    for (int i = 0; i < 4; ++i) {   // B: w1t rows (h-cols)
      int L = i * 4096 + tid * 16;
      int row = i * 32 + (tid >> 3);
      gload16(wB + (size_t)row * CDIM + kk * BK + (kbs >> 1), smem + 16384 + L);
    }
  };

  auto compute = [&]() {
#pragma unroll
    for (int ks = 0; ks < 2; ++ks) {
      f16x8 af[4], bfr[4];
      int kb = ks * 64 + (lane >> 4) * 16;
#pragma unroll
      for (int fr = 0; fr < 4; ++fr) {
        int row = wr * 64 + fr * 16 + (lane & 15);
        af[fr] = *(const f16x8*)(smem + row * 128 + (kb ^ ((row & 7) << 4)));
      }
#pragma unroll
      for (int fc = 0; fc < 4; ++fc) {
        int col = wc * 64 + fc * 16 + (lane & 15);
        bfr[fc] = *(const f16x8*)(smem + 16384 + col * 128 + (kb ^ ((col & 7) << 4)));
      }
#pragma unroll
      for (int fr = 0; fr < 4; ++fr)
#pragma unroll
        for (int fc = 0; fc < 4; ++fc)
          acc[fr][fc] = __builtin_amdgcn_mfma_f32_16x16x32_f16(af[fr], bfr[fc],
                                                               acc[fr][fc], 0, 0, 0);
    }
  };

  stage(0);
  for (int kk = 0; kk < 8; ++kk) {
    __syncthreads();           // drains vmcnt: staged tile visible
    compute();
    __syncthreads();           // all reads done before restage
    if (kk < 7) stage(kk + 1);
  }

  // epilogue: gelu -> fp16, repack via LDS for coalesced 16B stores
#pragma unroll
  for (int fr = 0; fr < 4; ++fr)
#pragma unroll
    for (int fc = 0; fc < 4; ++fc)
#pragma unroll
      for (int i = 0; i < 4; ++i) {
        int row = wr * 64 + fr * 16 + (lane >> 4) * 4 + i;
        int col = wc * 64 + fc * 16 + (lane & 15);
        float v = gelu_erf(acc[fr][fc][i]);
        int off = (row * 256 + col * 2) ^ ((row & 7) << 4);
        *(f16*)(smem + off) = (f16)v;
      }
  __syncthreads();
  int colb = ((tid & 15) * 16) ^ (((tid >> 4) & 7) << 4);
#pragma unroll
  for (int j = 0; j < 8; ++j) {
    int L = j * 4096 + tid * 16;
    int row = j * 16 + (tid >> 4);
    uint4 v = *(const uint4*)(smem + row * 256 + colb);
    *(uint4*)((char*)H + ((size_t)(m0 + row) * FFC + (h0 - hq)) * 2 + (L & 255)) = v;
  }
}

// ---------------- pass 2: out[list[slot]] += wgt[slot] * (H[slot] @ W2e) ----------------

__global__ __launch_bounds__(256) void k_gemm2(const f16* __restrict__ H,
                                               const f16* __restrict__ w2t, // [E][C][FF]
                                               const int* __restrict__ list,
                                               const float* __restrict__ wgt,
                                               const int* __restrict__ base,
                                               float* __restrict__ out, int hq) {
  __shared__ __align__(16) char smem[32768 + 1024];
  int* slist = (int*)(smem + 32768);
  float* swgt = (float*)(smem + 32768 + 512);
  int tid = threadIdx.x;
  int m0 = blockIdx.x * BM;
  int c0 = blockIdx.y * BN;
  int e = 0;
#pragma unroll
  for (int i = 1; i < 4; ++i) if (m0 >= base[i]) e = i;
  if (tid < BM) {
    slist[tid] = list[m0 + tid];
    swgt[tid] = wgt[m0 + tid];
  }
  __syncthreads();

  const f16* pA = H + (size_t)m0 * FFC;
  const f16* wB = w2t + (size_t)(e * CDIM + c0) * FF + hq;
  int kbs = ((tid & 7) * 16) ^ (((tid >> 3) & 7) << 4);

  f32x4 acc[4][4] = {};
  int lane = tid & 63, w = tid >> 6, wr = w >> 1, wc = w & 1;

  auto stage = [&](int kk) {
#pragma unroll
    for (int i = 0; i < 4; ++i) {   // A: H rows (slots, direct)
      int L = i * 4096 + tid * 16;
      int row = i * 32 + (tid >> 3);
      gload16(pA + (size_t)row * FFC + kk * BK + (kbs >> 1), smem + L);
    }
#pragma unroll
    for (int i = 0; i < 4; ++i) {   // B: w2t rows (out-cols)
      int L = i * 4096 + tid * 16;
      int row = i * 32 + (tid >> 3);
      gload16(wB + (size_t)row * FF + kk * BK + (kbs >> 1), smem + 16384 + L);
    }
  };

  auto compute = [&]() {
#pragma unroll
    for (int ks = 0; ks < 2; ++ks) {
      f16x8 af[4], bfr[4];
      int kb = ks * 64 + (lane >> 4) * 16;
#pragma unroll
      for (int fr = 0; fr < 4; ++fr) {
        int row = wr * 64 + fr * 16 + (lane & 15);
        af[fr] = *(const f16x8*)(smem + row * 128 + (kb ^ ((row & 7) << 4)));
      }
#pragma unroll
      for (int fc = 0; fc < 4; ++fc) {
        int col = wc * 64 + fc * 16 + (lane & 15);
        bfr[fc] = *(const f16x8*)(smem + 16384 + col * 128 + (kb ^ ((col & 7) << 4)));
      }
#pragma unroll
      for (int fr = 0; fr < 4; ++fr)
#pragma unroll
        for (int fc = 0; fc < 4; ++fc)
          acc[fr][fc] = __builtin_amdgcn_mfma_f32_16x16x32_f16(af[fr], bfr[fc],
                                                               acc[fr][fc], 0, 0, 0);
    }
  };

  stage(0);
  for (int kk = 0; kk < 8; ++kk) {
    __syncthreads();
    compute();
    __syncthreads();
    if (kk < 7) stage(kk + 1);
  }

  // epilogue: weight & scatter-add (exactly 2 adds/elem/chunk -> commutative-exact)
#pragma unroll
  for (int fr = 0; fr < 4; ++fr) {
#pragma unroll
    for (int i = 0; i < 4; ++i) {
      int r = wr * 64 + fr * 16 + (lane >> 4) * 4 + i;
      int tok = slist[r];
      if (tok < 0) continue;
      float wv = swgt[r];
      float* orow = out + (size_t)tok * CDIM + c0 + wc * 64 + (lane & 15);
#pragma unroll
      for (int fc = 0; fc < 4; ++fc)
        atomicAdd(orow + fc * 16, acc[fr][fc][i] * wv);
    }
  }
}

// ---------------- host ----------------

extern "C" void kernel_launch(void* const* d_in, const int* in_sizes, int n_in,
                              void* d_out, int out_size, void* d_ws, size_t ws_size,
                              hipStream_t stream) {
  const float* x  = (const float*)d_in[0];
  const float* gw = (const float*)d_in[1];
  const float* w1 = (const float*)d_in[2];
  const float* w2 = (const float*)d_in[3];
  float* out  = (float*)d_out;
  float* rout = out + (size_t)NTOK * CDIM;

  char* ws = (char*)d_ws;
  f16* xh      = (f16*)ws;     ws += (size_t)NTOK * CDIM * 2;      // 16.78 MB
  f16* w1t     = (f16*)ws;     ws += (size_t)NEXP * FF * CDIM * 2; //  8.39 MB
  f16* w2t     = (f16*)ws;     ws += (size_t)NEXP * FF * CDIM * 2; //  8.39 MB
  f16* Hbuf    = (f16*)ws;     ws += (size_t)CAP * FFC * 2;        // 34.08 MB
  float4* tokinfo = (float4*)ws; ws += (size_t)NTOK * 16;          //  0.26 MB
  int* list    = (int*)ws;     ws += (size_t)CAP * 4;
  float* wgt   = (float*)ws;   ws += (size_t)CAP * 4;
  int* cnt     = (int*)ws;     ws += 4 * CPAD * 4;
  int* base    = (int*)ws;     ws += 64;
  int* cursor  = (int*)ws;     ws += 4 * CPAD * 4;

  k_zero<<<8192, 256, 0, stream>>>((float4*)out, NTOK * CDIM / 4);
  k_init<<<(CAP + 255) / 256, 256, 0, stream>>>(list, wgt, cnt);
  k_cast_t<<<dim3(FF / 64, CDIM / 64, NEXP), 256, 0, stream>>>(w1, w1t, CDIM, FF);
  k_cast_t<<<dim3(CDIM / 64, FF / 64, NEXP), 256, 0, stream>>>(w2, w2t, FF, CDIM);
  k_router<<<NTOK / 64, 256, 0, stream>>>(x, gw, xh, rout, tokinfo, cnt);
  k_bases<<<1, 64, 0, stream>>>(cnt, base, cursor);
  k_assign<<<NTOK / 1024, 256, 0, stream>>>(tokinfo, cursor, list, wgt);

  for (int q = 0; q < NQ; ++q) {
    k_gemm1<<<dim3(CAP / BM, FFC / BN), 256, 0, stream>>>(xh, w1t, list, base,
                                                          Hbuf, q * FFC);
    k_gemm2<<<dim3(CAP / BM, CDIM / BN), 256, 0, stream>>>(Hbuf, w2t, list, wgt,
                                                           base, out, q * FFC);
  }
}

// Round 3
// 528.145 us; speedup vs baseline: 2.0792x; 1.0658x over previous
//
#include <hip/hip_runtime.h>
#include <hip/hip_fp16.h>

// DSMoE: x(8,2048,512) f32, gate_w(512,4), w1(4,512,2048), w2(4,2048,512)
// out = [ (8,2048,512) f32 ; router_sparse (16384,4) f32 ]
// R3: M-chunked two-pass (full-K gemm2, K=2048), Y fp16 + gather-combine.
//     Zero atomics in hot path (R2: 68M atomicAdds = 294us in gemm2).

#define NTOK  16384
#define CDIM  512
#define FF    2048
#define NEXP  4
#define CAP   33280    // 32768 + 4*128 padding headroom (260 blocks of 128)
#define NBLK  260
#define BM    128
#define BN1   128      // gemm1 N-tile (ff cols)
#define BN2   64       // gemm2 N-tile (out cols)
#define BK    64
#define CPAD  32       // ints per counter line (128B)

typedef _Float16 f16;
typedef __attribute__((ext_vector_type(8))) _Float16 f16x8;
typedef __attribute__((ext_vector_type(4))) _Float16 f16x4;
typedef __attribute__((ext_vector_type(4))) float f32x4;

__device__ __forceinline__ void gload16(const void* g, void* l) {
  __builtin_amdgcn_global_load_lds(
      (const __attribute__((address_space(1))) unsigned int*)g,
      (__attribute__((address_space(3))) unsigned int*)l, 16, 0, 0);
}

__device__ __forceinline__ float gelu_erf(float v) {
  return 0.5f * v * (1.0f + erff(v * 0.70710678118654752440f));
}

// ---------------- small utility kernels ----------------

__global__ __launch_bounds__(256) void k_init(int* list, int* cnt) {
  int i = blockIdx.x * 256 + threadIdx.x;
  if (i < CAP) list[i] = -1;
  if (i < 4) cnt[i * CPAD] = 0;
}

// transpose-cast: in [E][R][Cc] f32 -> out [E][Cc][R] f16, 64x64 tiles
__global__ __launch_bounds__(256) void k_cast_t(const float* __restrict__ in,
                                                f16* __restrict__ out, int R, int Cc) {
  __shared__ f16 T[64][72];
  int ez = blockIdx.z;
  const float* ine = in + (size_t)ez * R * Cc;
  f16* oute = out + (size_t)ez * R * Cc;
  int c0 = blockIdx.x * 64;
  int r0 = blockIdx.y * 64;
  int t = threadIdx.x;
  {
    int rr = t >> 2, cc = (t & 3) * 16;
    const float* src = ine + (size_t)(r0 + rr) * Cc + c0 + cc;
    union { f16 h[16]; uint4 u[2]; } pk;
#pragma unroll
    for (int j = 0; j < 16; j += 4) {
      float4 a = *(const float4*)(src + j);
      pk.h[j] = (f16)a.x; pk.h[j + 1] = (f16)a.y;
      pk.h[j + 2] = (f16)a.z; pk.h[j + 3] = (f16)a.w;
    }
    *(uint4*)&T[rr][cc] = pk.u[0];
    *(uint4*)&T[rr][cc + 8] = pk.u[1];
  }
  __syncthreads();
  {
    int oc = t >> 2, orr = (t & 3) * 16;
    union { f16 h[16]; uint4 u[2]; } pk;
#pragma unroll
    for (int j = 0; j < 16; ++j) pk.h[j] = T[orr + j][oc];
    f16* dst = oute + (size_t)(c0 + oc) * R + r0 + orr;
    *(uint4*)dst = pk.u[0];
    *(uint4*)(dst + 8) = pk.u[1];
  }
}

// ---------------- router (fp32 exact) + fused x->fp16 cast ----------------

__global__ __launch_bounds__(256) void k_router(const float* __restrict__ x,
                                                const float* __restrict__ gw,
                                                f16* __restrict__ xh,
                                                float* __restrict__ rout,
                                                float4* __restrict__ tokinfo,
                                                int* __restrict__ cnt) {
  __shared__ int lcnt[4];
  int tid = threadIdx.x;
  if (tid < 4) lcnt[tid] = 0;
  __syncthreads();
  int wv = tid >> 6, lane = tid & 63;
  const float4* g = ((const float4*)gw) + lane * 8;
  float4 gv[8];
#pragma unroll
  for (int j = 0; j < 8; ++j) gv[j] = g[j];

  int tok0 = blockIdx.x * 64 + wv * 16;
  for (int i = 0; i < 16; ++i) {
    int tok = tok0 + i;
    const float4* xr = (const float4*)(x + (size_t)tok * CDIM + lane * 8);
    float4 a0 = xr[0], a1 = xr[1];
    union { f16 h[8]; uint4 u; } pk;
    pk.h[0] = (f16)a0.x; pk.h[1] = (f16)a0.y; pk.h[2] = (f16)a0.z; pk.h[3] = (f16)a0.w;
    pk.h[4] = (f16)a1.x; pk.h[5] = (f16)a1.y; pk.h[6] = (f16)a1.z; pk.h[7] = (f16)a1.w;
    *(uint4*)(xh + (size_t)tok * CDIM + lane * 8) = pk.u;
    float xv[8] = {a0.x, a0.y, a0.z, a0.w, a1.x, a1.y, a1.z, a1.w};
    float l0 = 0, l1 = 0, l2 = 0, l3 = 0;
#pragma unroll
    for (int j = 0; j < 8; ++j) {
      float4 g4 = gv[j];
      l0 = fmaf(xv[j], g4.x, l0); l1 = fmaf(xv[j], g4.y, l1);
      l2 = fmaf(xv[j], g4.z, l2); l3 = fmaf(xv[j], g4.w, l3);
    }
#pragma unroll
    for (int off = 32; off; off >>= 1) {
      l0 += __shfl_xor(l0, off); l1 += __shfl_xor(l1, off);
      l2 += __shfl_xor(l2, off); l3 += __shfl_xor(l3, off);
    }
    if (lane == 0) {
      float lg[4] = {l0, l1, l2, l3};
      float m = fmaxf(fmaxf(lg[0], lg[1]), fmaxf(lg[2], lg[3]));
      float p[4], s = 0.f;
#pragma unroll
      for (int e = 0; e < 4; ++e) { p[e] = expf(lg[e] - m); s += p[e]; }
      int i0 = 0;
#pragma unroll
      for (int e = 1; e < 4; ++e) if (lg[e] > lg[i0]) i0 = e;
      int i1 = -1;
#pragma unroll
      for (int e = 0; e < 4; ++e)
        if (e != i0 && (i1 < 0 || lg[e] > lg[i1])) i1 = e;
      float p0 = p[i0] / s, p1 = p[i1] / s;
      float ss = fmaxf(p0 + p1, 1e-6f);
      float w0 = p0 / ss, w1v = p1 / ss;
      float r[4] = {0.f, 0.f, 0.f, 0.f};
      r[i0] = w0; r[i1] = w1v;
      *(float4*)(rout + tok * 4) = make_float4(r[0], r[1], r[2], r[3]);
      float4 ti;
      ti.x = __int_as_float(i0); ti.y = __int_as_float(i1); ti.z = w0; ti.w = w1v;
      tokinfo[tok] = ti;
      atomicAdd(&lcnt[i0], 1);
      atomicAdd(&lcnt[i1], 1);
    }
  }
  __syncthreads();
  if (tid < 4) atomicAdd(cnt + tid * CPAD, lcnt[tid]);
}

__global__ void k_bases(const int* __restrict__ cnt, int* __restrict__ base,
                        int* __restrict__ cursor) {
  if (threadIdx.x == 0 && blockIdx.x == 0) {
    int b = 0;
#pragma unroll
    for (int e = 0; e < 4; ++e) {
      base[e] = b; cursor[e * CPAD] = b;
      b += (cnt[e * CPAD] + 127) & ~127;
    }
    base[4] = b;
  }
}

// slot assignment + inverse map (token -> its 2 slots)
__global__ __launch_bounds__(256) void k_assign(const float4* __restrict__ tokinfo,
                                                int* cursor, int* __restrict__ list,
                                                int2* __restrict__ tokslot) {
  __shared__ int lcnt[4], lbase[4];
  int tid = threadIdx.x;
  if (tid < 4) lcnt[tid] = 0;
  __syncthreads();
  int t0 = blockIdx.x * 1024 + tid * 4;
  float4 ti[4]; int lo0[4], lo1[4];
#pragma unroll
  for (int j = 0; j < 4; ++j) {
    ti[j] = tokinfo[t0 + j];
    lo0[j] = atomicAdd(&lcnt[__float_as_int(ti[j].x)], 1);
    lo1[j] = atomicAdd(&lcnt[__float_as_int(ti[j].y)], 1);
  }
  __syncthreads();
  if (tid < 4) lbase[tid] = atomicAdd(cursor + tid * CPAD, lcnt[tid]);
  __syncthreads();
#pragma unroll
  for (int j = 0; j < 4; ++j) {
    int s0 = lbase[__float_as_int(ti[j].x)] + lo0[j];
    list[s0] = t0 + j;
    int s1 = lbase[__float_as_int(ti[j].y)] + lo1[j];
    list[s1] = t0 + j;
    tokslot[t0 + j] = make_int2(s0, s1);
  }
}

// ---------------- pass 1: H[slot_local, 0..FF) = gelu(x[list] @ W1e) ----------------

__global__ __launch_bounds__(256) void k_gemm1(const f16* __restrict__ xh,
                                               const f16* __restrict__ w1t, // [E][FF][C]
                                               const int* __restrict__ list,
                                               const int* __restrict__ base,
                                               f16* __restrict__ H, int cb) {
  __shared__ __align__(16) char smem[32768 + 512];
  int* slist = (int*)(smem + 32768);
  int tid = threadIdx.x;
  int m0 = (cb + blockIdx.x) * BM;        // global slot
  int mloc = blockIdx.x * BM;             // chunk-local slot
  int h0 = blockIdx.y * BN1;              // ff col
  int e = 0;
#pragma unroll
  for (int i = 1; i < 4; ++i) if (m0 >= base[i]) e = i;
  if (tid < BM) {
    int v = list[m0 + tid];
    slist[tid] = v < 0 ? 0 : v;   // clamp pads -> finite garbage, never read back
  }
  __syncthreads();

  int tokr[4];
#pragma unroll
  for (int i = 0; i < 4; ++i) tokr[i] = slist[i * 32 + (tid >> 3)];

  const f16* wB = w1t + (size_t)(e * FF + h0) * CDIM;
  int kbs = ((tid & 7) * 16) ^ (((tid >> 3) & 7) << 4);

  f32x4 acc[4][4] = {};
  int lane = tid & 63, w = tid >> 6, wr = w >> 1, wc = w & 1;

  auto stage = [&](int kk) {
#pragma unroll
    for (int i = 0; i < 4; ++i) {   // A: gathered x rows
      int L = i * 4096 + tid * 16;
      gload16(xh + (size_t)tokr[i] * CDIM + kk * BK + (kbs >> 1), smem + L);
    }
#pragma unroll
    for (int i = 0; i < 4; ++i) {   // B: w1t rows (ff cols)
      int L = i * 4096 + tid * 16;
      int row = i * 32 + (tid >> 3);
      gload16(wB + (size_t)row * CDIM + kk * BK + (kbs >> 1), smem + 16384 + L);
    }
  };

  auto compute = [&]() {
#pragma unroll
    for (int ks = 0; ks < 2; ++ks) {
      f16x8 af[4], bfr[4];
      int kb = ks * 64 + (lane >> 4) * 16;
#pragma unroll
      for (int fr = 0; fr < 4; ++fr) {
        int row = wr * 64 + fr * 16 + (lane & 15);
        af[fr] = *(const f16x8*)(smem + row * 128 + (kb ^ ((row & 7) << 4)));
      }
#pragma unroll
      for (int fc = 0; fc < 4; ++fc) {
        int col = wc * 64 + fc * 16 + (lane & 15);
        bfr[fc] = *(const f16x8*)(smem + 16384 + col * 128 + (kb ^ ((col & 7) << 4)));
      }
#pragma unroll
      for (int fr = 0; fr < 4; ++fr)
#pragma unroll
        for (int fc = 0; fc < 4; ++fc)
          acc[fr][fc] = __builtin_amdgcn_mfma_f32_16x16x32_f16(af[fr], bfr[fc],
                                                               acc[fr][fc], 0, 0, 0);
    }
  };

  stage(0);
  for (int kk = 0; kk < 8; ++kk) {   // K = CDIM = 512
    __syncthreads();
    compute();
    __syncthreads();
    if (kk < 7) stage(kk + 1);
  }

  // epilogue: gelu -> fp16, LDS repack, coalesced 16B stores (H row stride FF)
#pragma unroll
  for (int fr = 0; fr < 4; ++fr)
#pragma unroll
    for (int fc = 0; fc < 4; ++fc)
#pragma unroll
      for (int i = 0; i < 4; ++i) {
        int row = wr * 64 + fr * 16 + (lane >> 4) * 4 + i;
        int col = wc * 64 + fc * 16 + (lane & 15);
        float v = gelu_erf(acc[fr][fc][i]);
        int off = (row * 256 + col * 2) ^ ((row & 7) << 4);
        *(f16*)(smem + off) = (f16)v;
      }
  __syncthreads();
#pragma unroll
  for (int j = 0; j < 8; ++j) {
    int row = j * 16 + (tid >> 4);
    int colb = ((tid & 15) * 16) ^ ((row & 7) << 4);
    uint4 v = *(const uint4*)(smem + row * 256 + colb);
    *(uint4*)((char*)H + ((size_t)(mloc + row) * FF + h0) * 2 + (tid & 15) * 16) = v;
  }
}

// ---------------- pass 2: Y[slot] = H[slot_local] @ W2e  (K = FF = 2048) ----------------

__global__ __launch_bounds__(256) void k_gemm2(const f16* __restrict__ H,
                                               const f16* __restrict__ w2t, // [E][C][FF]
                                               const int* __restrict__ base,
                                               f16* __restrict__ Y, int cb) {
  __shared__ __align__(16) char smem[24576];
  int tid = threadIdx.x;
  int m0 = (cb + blockIdx.x) * BM;
  int mloc = blockIdx.x * BM;
  int c0 = blockIdx.y * BN2;
  int e = 0;
#pragma unroll
  for (int i = 1; i < 4; ++i) if (m0 >= base[i]) e = i;

  const f16* pA = H + (size_t)mloc * FF;
  const f16* wB = w2t + (size_t)(e * CDIM + c0) * FF;
  int kbs = ((tid & 7) * 16) ^ (((tid >> 3) & 7) << 4);

  f32x4 acc[4][2] = {};
  int lane = tid & 63, w = tid >> 6, wr = w >> 1, wc = w & 1;

  auto stage = [&](int kk) {
#pragma unroll
    for (int i = 0; i < 4; ++i) {   // A: H rows (local slots)
      int L = i * 4096 + tid * 16;
      int row = i * 32 + (tid >> 3);
      gload16(pA + (size_t)row * FF + kk * BK + (kbs >> 1), smem + L);
    }
#pragma unroll
    for (int i = 0; i < 2; ++i) {   // B: w2t rows (out cols), 8KB
      int L = i * 4096 + tid * 16;
      int row = i * 32 + (tid >> 3);
      gload16(wB + (size_t)row * FF + kk * BK + (kbs >> 1), smem + 16384 + L);
    }
  };

  auto compute = [&]() {
#pragma unroll
    for (int ks = 0; ks < 2; ++ks) {
      f16x8 af[4], bfr[2];
      int kb = ks * 64 + (lane >> 4) * 16;
#pragma unroll
      for (int fr = 0; fr < 4; ++fr) {
        int row = wr * 64 + fr * 16 + (lane & 15);
        af[fr] = *(const f16x8*)(smem + row * 128 + (kb ^ ((row & 7) << 4)));
      }
#pragma unroll
      for (int fc = 0; fc < 2; ++fc) {
        int col = wc * 32 + fc * 16 + (lane & 15);
        bfr[fc] = *(const f16x8*)(smem + 16384 + col * 128 + (kb ^ ((col & 7) << 4)));
      }
#pragma unroll
      for (int fr = 0; fr < 4; ++fr)
#pragma unroll
        for (int fc = 0; fc < 2; ++fc)
          acc[fr][fc] = __builtin_amdgcn_mfma_f32_16x16x32_f16(af[fr], bfr[fc],
                                                               acc[fr][fc], 0, 0, 0);
    }
  };

  stage(0);
  for (int kk = 0; kk < 32; ++kk) {   // K = FF = 2048
    __syncthreads();
    compute();
    __syncthreads();
    if (kk < 31) stage(kk + 1);
  }

  // epilogue: fp16 Y rows, LDS repack [128][64] f16, plain coalesced stores
#pragma unroll
  for (int fr = 0; fr < 4; ++fr)
#pragma unroll
    for (int fc = 0; fc < 2; ++fc)
#pragma unroll
      for (int i = 0; i < 4; ++i) {
        int row = wr * 64 + fr * 16 + (lane >> 4) * 4 + i;
        int col = wc * 32 + fc * 16 + (lane & 15);
        int off = (row * 128 + col * 2) ^ ((row & 7) << 4);
        *(f16*)(smem + off) = (f16)acc[fr][fc][i];
      }
  __syncthreads();
#pragma unroll
  for (int j = 0; j < 4; ++j) {
    int row = j * 32 + (tid >> 3);
    int colb = ((tid & 7) * 16) ^ ((row & 7) << 4);
    uint4 v = *(const uint4*)(smem + row * 128 + colb);
    *(uint4*)((char*)Y + ((size_t)(m0 + row) * CDIM + c0) * 2 + (tid & 7) * 16) = v;
  }
}

// ---------------- combine: out[tok] = w0*Y[s0] + w1*Y[s1] ----------------

__global__ __launch_bounds__(256) void k_combine(const f16* __restrict__ Y,
                                                 const float4* __restrict__ tokinfo,
                                                 const int2* __restrict__ tokslot,
                                                 float* __restrict__ out) {
  int gid = blockIdx.x * 256 + threadIdx.x;
  int tok = gid >> 7;
  int cc = (gid & 127) * 4;
  int2 sl = tokslot[tok];
  float4 ti = tokinfo[tok];
  f16x4 y0 = *(const f16x4*)(Y + (size_t)sl.x * CDIM + cc);
  f16x4 y1 = *(const f16x4*)(Y + (size_t)sl.y * CDIM + cc);
  float w0 = ti.z, w1 = ti.w;
  float4 o;
  o.x = w0 * (float)y0[0] + w1 * (float)y1[0];
  o.y = w0 * (float)y0[1] + w1 * (float)y1[1];
  o.z = w0 * (float)y0[2] + w1 * (float)y1[2];
  o.w = w0 * (float)y0[3] + w1 * (float)y1[3];
  *(float4*)(out + (size_t)tok * CDIM + cc) = o;
}

// ---------------- host ----------------

extern "C" void kernel_launch(void* const* d_in, const int* in_sizes, int n_in,
                              void* d_out, int out_size, void* d_ws, size_t ws_size,
                              hipStream_t stream) {
  const float* x  = (const float*)d_in[0];
  const float* gw = (const float*)d_in[1];
  const float* w1 = (const float*)d_in[2];
  const float* w2 = (const float*)d_in[3];
  float* out  = (float*)d_out;
  float* rout = out + (size_t)NTOK * CDIM;

  char* ws = (char*)d_ws;
  f16* xh      = (f16*)ws;      ws += (size_t)NTOK * CDIM * 2;       // 16.78 MB
  f16* w1t     = (f16*)ws;      ws += (size_t)NEXP * FF * CDIM * 2;  //  8.39 MB
  f16* w2t     = (f16*)ws;      ws += (size_t)NEXP * FF * CDIM * 2;  //  8.39 MB
  f16* Ybuf    = (f16*)ws;      ws += (size_t)CAP * CDIM * 2;        // 34.08 MB
  float4* tokinfo = (float4*)ws; ws += (size_t)NTOK * 16;            //  0.26 MB
  int2* tokslot = (int2*)ws;    ws += (size_t)NTOK * 8;              //  0.13 MB
  int* list    = (int*)ws;      ws += (size_t)CAP * 4;               //  0.13 MB
  int* cnt     = (int*)ws;      ws += 4 * CPAD * 4;
  int* base    = (int*)ws;      ws += 64;
  int* cursor  = (int*)ws;      ws += 4 * CPAD * 4;
  f16* Hbuf    = (f16*)ws;      // CB*128*FF fp16, sized by ladder below

  size_t base_bytes = (size_t)(ws - (char*)d_ws);
  // pick the largest chunk (in 128-slot blocks) whose H buffer fits ws
  const int opts[10] = {65, 52, 26, 20, 13, 10, 5, 4, 2, 1};
  int CB = 1;
  for (int oi = 0; oi < 10; ++oi) {
    if (base_bytes + (size_t)opts[oi] * BM * FF * 2 <= ws_size) { CB = opts[oi]; break; }
  }

  k_init<<<(CAP + 255) / 256, 256, 0, stream>>>(list, cnt);
  k_cast_t<<<dim3(FF / 64, CDIM / 64, NEXP), 256, 0, stream>>>(w1, w1t, CDIM, FF);
  k_cast_t<<<dim3(CDIM / 64, FF / 64, NEXP), 256, 0, stream>>>(w2, w2t, FF, CDIM);
  k_router<<<NTOK / 64, 256, 0, stream>>>(x, gw, xh, rout, tokinfo, cnt);
  k_bases<<<1, 64, 0, stream>>>(cnt, base, cursor);
  k_assign<<<NTOK / 1024, 256, 0, stream>>>(tokinfo, cursor, list, tokslot);

  for (int cb = 0; cb < NBLK; cb += CB) {
    k_gemm1<<<dim3(CB, FF / BN1), 256, 0, stream>>>(xh, w1t, list, base, Hbuf, cb);
    k_gemm2<<<dim3(CB, CDIM / BN2), 256, 0, stream>>>(Hbuf, w2t, base, Ybuf, cb);
  }
  k_combine<<<NTOK * CDIM / 4 / 256, 256, 0, stream>>>(Ybuf, tokinfo, tokslot, out);
}

// Round 4
// 375.128 us; speedup vs baseline: 2.9273x; 1.4079x over previous
//
#include <hip/hip_runtime.h>
#include <hip/hip_fp16.h>

// DSMoE: x(8,2048,512) f32, gate_w(512,4), w1(4,512,2048), w2(4,2048,512)
// out = [ (8,2048,512) f32 ; router_sparse (16384,4) f32 ]
// R4: fast A&S-erf gelu (R3: erff epilogue = 37% VALUBusy in gemm1);
//     bijective XCD swizzle, y-fast work order (R3: 77MB L2-miss fetch vs 13MB unique).

#define NTOK  16384
#define CDIM  512
#define FF    2048
#define NEXP  4
#define CAP   33280    // 32768 + 4*128 padding headroom (260 blocks of 128)
#define NBLK  260
#define BM    128
#define BN1   128      // gemm1 N-tile (ff cols)
#define BN2   64       // gemm2 N-tile (out cols)
#define BK    64
#define CPAD  32       // ints per counter line (128B)

typedef _Float16 f16;
typedef __attribute__((ext_vector_type(8))) _Float16 f16x8;
typedef __attribute__((ext_vector_type(4))) _Float16 f16x4;
typedef __attribute__((ext_vector_type(4))) float f32x4;

__device__ __forceinline__ void gload16(const void* g, void* l) {
  __builtin_amdgcn_global_load_lds(
      (const __attribute__((address_space(1))) unsigned int*)g,
      (__attribute__((address_space(3))) unsigned int*)l, 16, 0, 0);
}

// gelu(v) = 0.5 v (1 + erf(v/sqrt2)), erf via Abramowitz-Stegun 7.1.26
// (max err 1.5e-7; raw v_rcp/v_exp). ~14 VALU ops vs libm erff's ~35.
__device__ __forceinline__ float gelu_fast(float v) {
  float az = fabsf(v) * 0.7071067811865476f;
  float t = __builtin_amdgcn_rcpf(fmaf(0.3275911f, az, 1.0f));
  float p = fmaf(fmaf(fmaf(fmaf(1.061405429f, t, -1.453152027f), t,
                           1.421413741f), t, -0.284496736f), t, 0.254829592f) * t;
  float e = __builtin_amdgcn_exp2f(az * az * -1.4426950408889634f);
  float erfa = fmaf(-p, e, 1.0f);          // erf(|v|/sqrt2)
  float u = copysignf(erfa, v);
  return 0.5f * v * (1.0f + u);
}

// bijective XCD swizzle (nwg % 8 == 0 for all grids used here)
__device__ __forceinline__ int xcd_swz(int bid, int nwg) {
  return (bid & 7) * (nwg >> 3) + (bid >> 3);
}

// ---------------- small utility kernels ----------------

__global__ __launch_bounds__(256) void k_init(int* list, int* cnt) {
  int i = blockIdx.x * 256 + threadIdx.x;
  if (i < CAP) list[i] = -1;
  if (i < 4) cnt[i * CPAD] = 0;
}

// transpose-cast: in [E][R][Cc] f32 -> out [E][Cc][R] f16, 64x64 tiles
__global__ __launch_bounds__(256) void k_cast_t(const float* __restrict__ in,
                                                f16* __restrict__ out, int R, int Cc) {
  __shared__ f16 T[64][72];
  int ez = blockIdx.z;
  const float* ine = in + (size_t)ez * R * Cc;
  f16* oute = out + (size_t)ez * R * Cc;
  int c0 = blockIdx.x * 64;
  int r0 = blockIdx.y * 64;
  int t = threadIdx.x;
  {
    int rr = t >> 2, cc = (t & 3) * 16;
    const float* src = ine + (size_t)(r0 + rr) * Cc + c0 + cc;
    union { f16 h[16]; uint4 u[2]; } pk;
#pragma unroll
    for (int j = 0; j < 16; j += 4) {
      float4 a = *(const float4*)(src + j);
      pk.h[j] = (f16)a.x; pk.h[j + 1] = (f16)a.y;
      pk.h[j + 2] = (f16)a.z; pk.h[j + 3] = (f16)a.w;
    }
    *(uint4*)&T[rr][cc] = pk.u[0];
    *(uint4*)&T[rr][cc + 8] = pk.u[1];
  }
  __syncthreads();
  {
    int oc = t >> 2, orr = (t & 3) * 16;
    union { f16 h[16]; uint4 u[2]; } pk;
#pragma unroll
    for (int j = 0; j < 16; ++j) pk.h[j] = T[orr + j][oc];
    f16* dst = oute + (size_t)(c0 + oc) * R + r0 + orr;
    *(uint4*)dst = pk.u[0];
    *(uint4*)(dst + 8) = pk.u[1];
  }
}

// ---------------- router (fp32 exact) + fused x->fp16 cast ----------------

__global__ __launch_bounds__(256) void k_router(const float* __restrict__ x,
                                                const float* __restrict__ gw,
                                                f16* __restrict__ xh,
                                                float* __restrict__ rout,
                                                float4* __restrict__ tokinfo,
                                                int* __restrict__ cnt) {
  __shared__ int lcnt[4];
  int tid = threadIdx.x;
  if (tid < 4) lcnt[tid] = 0;
  __syncthreads();
  int wv = tid >> 6, lane = tid & 63;
  const float4* g = ((const float4*)gw) + lane * 8;
  float4 gv[8];
#pragma unroll
  for (int j = 0; j < 8; ++j) gv[j] = g[j];

  int tok0 = blockIdx.x * 64 + wv * 16;
  for (int i = 0; i < 16; ++i) {
    int tok = tok0 + i;
    const float4* xr = (const float4*)(x + (size_t)tok * CDIM + lane * 8);
    float4 a0 = xr[0], a1 = xr[1];
    union { f16 h[8]; uint4 u; } pk;
    pk.h[0] = (f16)a0.x; pk.h[1] = (f16)a0.y; pk.h[2] = (f16)a0.z; pk.h[3] = (f16)a0.w;
    pk.h[4] = (f16)a1.x; pk.h[5] = (f16)a1.y; pk.h[6] = (f16)a1.z; pk.h[7] = (f16)a1.w;
    *(uint4*)(xh + (size_t)tok * CDIM + lane * 8) = pk.u;
    float xv[8] = {a0.x, a0.y, a0.z, a0.w, a1.x, a1.y, a1.z, a1.w};
    float l0 = 0, l1 = 0, l2 = 0, l3 = 0;
#pragma unroll
    for (int j = 0; j < 8; ++j) {
      float4 g4 = gv[j];
      l0 = fmaf(xv[j], g4.x, l0); l1 = fmaf(xv[j], g4.y, l1);
      l2 = fmaf(xv[j], g4.z, l2); l3 = fmaf(xv[j], g4.w, l3);
    }
#pragma unroll
    for (int off = 32; off; off >>= 1) {
      l0 += __shfl_xor(l0, off); l1 += __shfl_xor(l1, off);
      l2 += __shfl_xor(l2, off); l3 += __shfl_xor(l3, off);
    }
    if (lane == 0) {
      float lg[4] = {l0, l1, l2, l3};
      float m = fmaxf(fmaxf(lg[0], lg[1]), fmaxf(lg[2], lg[3]));
      float p[4], s = 0.f;
#pragma unroll
      for (int e = 0; e < 4; ++e) { p[e] = expf(lg[e] - m); s += p[e]; }
      int i0 = 0;
#pragma unroll
      for (int e = 1; e < 4; ++e) if (lg[e] > lg[i0]) i0 = e;
      int i1 = -1;
#pragma unroll
      for (int e = 0; e < 4; ++e)
        if (e != i0 && (i1 < 0 || lg[e] > lg[i1])) i1 = e;
      float p0 = p[i0] / s, p1 = p[i1] / s;
      float ss = fmaxf(p0 + p1, 1e-6f);
      float w0 = p0 / ss, w1v = p1 / ss;
      float r[4] = {0.f, 0.f, 0.f, 0.f};
      r[i0] = w0; r[i1] = w1v;
      *(float4*)(rout + tok * 4) = make_float4(r[0], r[1], r[2], r[3]);
      float4 ti;
      ti.x = __int_as_float(i0); ti.y = __int_as_float(i1); ti.z = w0; ti.w = w1v;
      tokinfo[tok] = ti;
      atomicAdd(&lcnt[i0], 1);
      atomicAdd(&lcnt[i1], 1);
    }
  }
  __syncthreads();
  if (tid < 4) atomicAdd(cnt + tid * CPAD, lcnt[tid]);
}

__global__ void k_bases(const int* __restrict__ cnt, int* __restrict__ base,
                        int* __restrict__ cursor) {
  if (threadIdx.x == 0 && blockIdx.x == 0) {
    int b = 0;
#pragma unroll
    for (int e = 0; e < 4; ++e) {
      base[e] = b; cursor[e * CPAD] = b;
      b += (cnt[e * CPAD] + 127) & ~127;
    }
    base[4] = b;
  }
}

// slot assignment + inverse map (token -> its 2 slots)
__global__ __launch_bounds__(256) void k_assign(const float4* __restrict__ tokinfo,
                                                int* cursor, int* __restrict__ list,
                                                int2* __restrict__ tokslot) {
  __shared__ int lcnt[4], lbase[4];
  int tid = threadIdx.x;
  if (tid < 4) lcnt[tid] = 0;
  __syncthreads();
  int t0 = blockIdx.x * 1024 + tid * 4;
  float4 ti[4]; int lo0[4], lo1[4];
#pragma unroll
  for (int j = 0; j < 4; ++j) {
    ti[j] = tokinfo[t0 + j];
    lo0[j] = atomicAdd(&lcnt[__float_as_int(ti[j].x)], 1);
    lo1[j] = atomicAdd(&lcnt[__float_as_int(ti[j].y)], 1);
  }
  __syncthreads();
  if (tid < 4) lbase[tid] = atomicAdd(cursor + tid * CPAD, lcnt[tid]);
  __syncthreads();
#pragma unroll
  for (int j = 0; j < 4; ++j) {
    int s0 = lbase[__float_as_int(ti[j].x)] + lo0[j];
    list[s0] = t0 + j;
    int s1 = lbase[__float_as_int(ti[j].y)] + lo1[j];
    list[s1] = t0 + j;
    tokslot[t0 + j] = make_int2(s0, s1);
  }
}

// ---------------- pass 1: H[slot_local, 0..FF) = gelu(x[list] @ W1e) ----------------
// 1-D grid (CB*16), XCD-swizzled, work = x*16 + y (y = ff panel, fastest).

__global__ __launch_bounds__(256) void k_gemm1(const f16* __restrict__ xh,
                                               const f16* __restrict__ w1t, // [E][FF][C]
                                               const int* __restrict__ list,
                                               const int* __restrict__ base,
                                               f16* __restrict__ H, int cb, int nwg) {
  __shared__ __align__(16) char smem[32768 + 512];
  int* slist = (int*)(smem + 32768);
  int tid = threadIdx.x;
  int wk = xcd_swz(blockIdx.x, nwg);
  int bx = wk >> 4, by = wk & 15;
  int m0 = (cb + bx) * BM;                // global slot
  int mloc = bx * BM;                     // chunk-local slot
  int h0 = by * BN1;                      // ff col
  int e = 0;
#pragma unroll
  for (int i = 1; i < 4; ++i) if (m0 >= base[i]) e = i;
  if (tid < BM) {
    int v = list[m0 + tid];
    slist[tid] = v < 0 ? 0 : v;   // clamp pads -> finite garbage, never read back
  }
  __syncthreads();

  int tokr[4];
#pragma unroll
  for (int i = 0; i < 4; ++i) tokr[i] = slist[i * 32 + (tid >> 3)];

  const f16* wB = w1t + (size_t)(e * FF + h0) * CDIM;
  int kbs = ((tid & 7) * 16) ^ (((tid >> 3) & 7) << 4);

  f32x4 acc[4][4] = {};
  int lane = tid & 63, w = tid >> 6, wr = w >> 1, wc = w & 1;

  auto stage = [&](int kk) {
#pragma unroll
    for (int i = 0; i < 4; ++i) {   // A: gathered x rows
      int L = i * 4096 + tid * 16;
      gload16(xh + (size_t)tokr[i] * CDIM + kk * BK + (kbs >> 1), smem + L);
    }
#pragma unroll
    for (int i = 0; i < 4; ++i) {   // B: w1t rows (ff cols)
      int L = i * 4096 + tid * 16;
      int row = i * 32 + (tid >> 3);
      gload16(wB + (size_t)row * CDIM + kk * BK + (kbs >> 1), smem + 16384 + L);
    }
  };

  auto compute = [&]() {
#pragma unroll
    for (int ks = 0; ks < 2; ++ks) {
      f16x8 af[4], bfr[4];
      int kb = ks * 64 + (lane >> 4) * 16;
#pragma unroll
      for (int fr = 0; fr < 4; ++fr) {
        int row = wr * 64 + fr * 16 + (lane & 15);
        af[fr] = *(const f16x8*)(smem + row * 128 + (kb ^ ((row & 7) << 4)));
      }
#pragma unroll
      for (int fc = 0; fc < 4; ++fc) {
        int col = wc * 64 + fc * 16 + (lane & 15);
        bfr[fc] = *(const f16x8*)(smem + 16384 + col * 128 + (kb ^ ((col & 7) << 4)));
      }
#pragma unroll
      for (int fr = 0; fr < 4; ++fr)
#pragma unroll
        for (int fc = 0; fc < 4; ++fc)
          acc[fr][fc] = __builtin_amdgcn_mfma_f32_16x16x32_f16(af[fr], bfr[fc],
                                                               acc[fr][fc], 0, 0, 0);
    }
  };

  stage(0);
  for (int kk = 0; kk < 8; ++kk) {   // K = CDIM = 512
    __syncthreads();
    compute();
    __syncthreads();
    if (kk < 7) stage(kk + 1);
  }

  // epilogue: gelu -> fp16, LDS repack, coalesced 16B stores (H row stride FF)
#pragma unroll
  for (int fr = 0; fr < 4; ++fr)
#pragma unroll
    for (int fc = 0; fc < 4; ++fc)
#pragma unroll
      for (int i = 0; i < 4; ++i) {
        int row = wr * 64 + fr * 16 + (lane >> 4) * 4 + i;
        int col = wc * 64 + fc * 16 + (lane & 15);
        float v = gelu_fast(acc[fr][fc][i]);
        int off = (row * 256 + col * 2) ^ ((row & 7) << 4);
        *(f16*)(smem + off) = (f16)v;
      }
  __syncthreads();
#pragma unroll
  for (int j = 0; j < 8; ++j) {
    int row = j * 16 + (tid >> 4);
    int colb = ((tid & 15) * 16) ^ ((row & 7) << 4);
    uint4 v = *(const uint4*)(smem + row * 256 + colb);
    *(uint4*)((char*)H + ((size_t)(mloc + row) * FF + h0) * 2 + (tid & 15) * 16) = v;
  }
}

// ---------------- pass 2: Y[slot] = H[slot_local] @ W2e  (K = FF = 2048) ----------------
// 1-D grid (CB*8), XCD-swizzled, work = x*8 + y (y = out panel, fastest).

__global__ __launch_bounds__(256) void k_gemm2(const f16* __restrict__ H,
                                               const f16* __restrict__ w2t, // [E][C][FF]
                                               const int* __restrict__ base,
                                               f16* __restrict__ Y, int cb, int nwg) {
  __shared__ __align__(16) char smem[24576];
  int tid = threadIdx.x;
  int wk = xcd_swz(blockIdx.x, nwg);
  int bx = wk >> 3, by = wk & 7;
  int m0 = (cb + bx) * BM;
  int mloc = bx * BM;
  int c0 = by * BN2;
  int e = 0;
#pragma unroll
  for (int i = 1; i < 4; ++i) if (m0 >= base[i]) e = i;

  const f16* pA = H + (size_t)mloc * FF;
  const f16* wB = w2t + (size_t)(e * CDIM + c0) * FF;
  int kbs = ((tid & 7) * 16) ^ (((tid >> 3) & 7) << 4);

  f32x4 acc[4][2] = {};
  int lane = tid & 63, w = tid >> 6, wr = w >> 1, wc = w & 1;

  auto stage = [&](int kk) {
#pragma unroll
    for (int i = 0; i < 4; ++i) {   // A: H rows (local slots)
      int L = i * 4096 + tid * 16;
      int row = i * 32 + (tid >> 3);
      gload16(pA + (size_t)row * FF + kk * BK + (kbs >> 1), smem + L);
    }
#pragma unroll
    for (int i = 0; i < 2; ++i) {   // B: w2t rows (out cols), 8KB
      int L = i * 4096 + tid * 16;
      int row = i * 32 + (tid >> 3);
      gload16(wB + (size_t)row * FF + kk * BK + (kbs >> 1), smem + 16384 + L);
    }
  };

  auto compute = [&]() {
#pragma unroll
    for (int ks = 0; ks < 2; ++ks) {
      f16x8 af[4], bfr[2];
      int kb = ks * 64 + (lane >> 4) * 16;
#pragma unroll
      for (int fr = 0; fr < 4; ++fr) {
        int row = wr * 64 + fr * 16 + (lane & 15);
        af[fr] = *(const f16x8*)(smem + row * 128 + (kb ^ ((row & 7) << 4)));
      }
#pragma unroll
      for (int fc = 0; fc < 2; ++fc) {
        int col = wc * 32 + fc * 16 + (lane & 15);
        bfr[fc] = *(const f16x8*)(smem + 16384 + col * 128 + (kb ^ ((col & 7) << 4)));
      }
#pragma unroll
      for (int fr = 0; fr < 4; ++fr)
#pragma unroll
        for (int fc = 0; fc < 2; ++fc)
          acc[fr][fc] = __builtin_amdgcn_mfma_f32_16x16x32_f16(af[fr], bfr[fc],
                                                               acc[fr][fc], 0, 0, 0);
    }
  };

  stage(0);
  for (int kk = 0; kk < 32; ++kk) {   // K = FF = 2048
    __syncthreads();
    compute();
    __syncthreads();
    if (kk < 31) stage(kk + 1);
  }

  // epilogue: fp16 Y rows, LDS repack [128][64] f16, plain coalesced stores
#pragma unroll
  for (int fr = 0; fr < 4; ++fr)
#pragma unroll
    for (int fc = 0; fc < 2; ++fc)
#pragma unroll
      for (int i = 0; i < 4; ++i) {
        int row = wr * 64 + fr * 16 + (lane >> 4) * 4 + i;
        int col = wc * 32 + fc * 16 + (lane & 15);
        int off = (row * 128 + col * 2) ^ ((row & 7) << 4);
        *(f16*)(smem + off) = (f16)acc[fr][fc][i];
      }
  __syncthreads();
#pragma unroll
  for (int j = 0; j < 4; ++j) {
    int row = j * 32 + (tid >> 3);
    int colb = ((tid & 7) * 16) ^ ((row & 7) << 4);
    uint4 v = *(const uint4*)(smem + row * 128 + colb);
    *(uint4*)((char*)Y + ((size_t)(m0 + row) * CDIM + c0) * 2 + (tid & 7) * 16) = v;
  }
}

// ---------------- combine: out[tok] = w0*Y[s0] + w1*Y[s1] ----------------

__global__ __launch_bounds__(256) void k_combine(const f16* __restrict__ Y,
                                                 const float4* __restrict__ tokinfo,
                                                 const int2* __restrict__ tokslot,
                                                 float* __restrict__ out) {
  int gid = blockIdx.x * 256 + threadIdx.x;
  int tok = gid >> 7;
  int cc = (gid & 127) * 4;
  int2 sl = tokslot[tok];
  float4 ti = tokinfo[tok];
  f16x4 y0 = *(const f16x4*)(Y + (size_t)sl.x * CDIM + cc);
  f16x4 y1 = *(const f16x4*)(Y + (size_t)sl.y * CDIM + cc);
  float w0 = ti.z, w1 = ti.w;
  float4 o;
  o.x = w0 * (float)y0[0] + w1 * (float)y1[0];
  o.y = w0 * (float)y0[1] + w1 * (float)y1[1];
  o.z = w0 * (float)y0[2] + w1 * (float)y1[2];
  o.w = w0 * (float)y0[3] + w1 * (float)y1[3];
  *(float4*)(out + (size_t)tok * CDIM + cc) = o;
}

// ---------------- host ----------------

extern "C" void kernel_launch(void* const* d_in, const int* in_sizes, int n_in,
                              void* d_out, int out_size, void* d_ws, size_t ws_size,
                              hipStream_t stream) {
  const float* x  = (const float*)d_in[0];
  const float* gw = (const float*)d_in[1];
  const float* w1 = (const float*)d_in[2];
  const float* w2 = (const float*)d_in[3];
  float* out  = (float*)d_out;
  float* rout = out + (size_t)NTOK * CDIM;

  char* ws = (char*)d_ws;
  f16* xh      = (f16*)ws;      ws += (size_t)NTOK * CDIM * 2;       // 16.78 MB
  f16* w1t     = (f16*)ws;      ws += (size_t)NEXP * FF * CDIM * 2;  //  8.39 MB
  f16* w2t     = (f16*)ws;      ws += (size_t)NEXP * FF * CDIM * 2;  //  8.39 MB
  f16* Ybuf    = (f16*)ws;      ws += (size_t)CAP * CDIM * 2;        // 34.08 MB
  float4* tokinfo = (float4*)ws; ws += (size_t)NTOK * 16;            //  0.26 MB
  int2* tokslot = (int2*)ws;    ws += (size_t)NTOK * 8;              //  0.13 MB
  int* list    = (int*)ws;      ws += (size_t)CAP * 4;               //  0.13 MB
  int* cnt     = (int*)ws;      ws += 4 * CPAD * 4;
  int* base    = (int*)ws;      ws += 64;
  int* cursor  = (int*)ws;      ws += 4 * CPAD * 4;
  f16* Hbuf    = (f16*)ws;      // CB*128*FF fp16, sized by ladder below

  size_t base_bytes = (size_t)(ws - (char*)d_ws);
  const int opts[10] = {65, 52, 26, 20, 13, 10, 5, 4, 2, 1};
  int CB = 1;
  for (int oi = 0; oi < 10; ++oi) {
    if (base_bytes + (size_t)opts[oi] * BM * FF * 2 <= ws_size) { CB = opts[oi]; break; }
  }

  k_init<<<(CAP + 255) / 256, 256, 0, stream>>>(list, cnt);
  k_cast_t<<<dim3(FF / 64, CDIM / 64, NEXP), 256, 0, stream>>>(w1, w1t, CDIM, FF);
  k_cast_t<<<dim3(CDIM / 64, FF / 64, NEXP), 256, 0, stream>>>(w2, w2t, FF, CDIM);
  k_router<<<NTOK / 64, 256, 0, stream>>>(x, gw, xh, rout, tokinfo, cnt);
  k_bases<<<1, 64, 0, stream>>>(cnt, base, cursor);
  k_assign<<<NTOK / 1024, 256, 0, stream>>>(tokinfo, cursor, list, tokslot);

  for (int cb = 0; cb < NBLK; cb += CB) {
    int n1 = CB * 16, n2 = CB * 8;
    k_gemm1<<<n1, 256, 0, stream>>>(xh, w1t, list, base, Hbuf, cb, n1);
    k_gemm2<<<n2, 256, 0, stream>>>(Hbuf, w2t, base, Ybuf, cb, n2);
  }
  k_combine<<<NTOK * CDIM / 4 / 256, 256, 0, stream>>>(Ybuf, tokinfo, tokslot, out);
}

// Round 5
// 305.657 us; speedup vs baseline: 3.5927x; 1.2273x over previous
//
#include <hip/hip_runtime.h>
#include <hip/hip_fp16.h>

// DSMoE: x(8,2048,512) f32, gate_w(512,4), w1(4,512,2048), w2(4,2048,512)
// out = [ (8,2048,512) f32 ; router_sparse (16384,4) f32 ]
// R5: T3-minimum pipelined K-loop (dbuf LDS, stage-before-compute, ONE barrier
//     per K-step). R4 had stage-after-compute + 2 barriers -> full load latency
//     exposed every K-step (MfmaUtil 14%).

#define NTOK  16384
#define CDIM  512
#define FF    2048
#define NEXP  4
#define CAP   33280    // 32768 + 4*128 padding headroom (260 blocks of 128)
#define NBLK  260
#define BM    128
#define BN1   128      // gemm1 N-tile (ff cols)
#define BN2   64       // gemm2 N-tile (out cols)
#define BK    64
#define CPAD  32       // ints per counter line (128B)

typedef _Float16 f16;
typedef __attribute__((ext_vector_type(8))) _Float16 f16x8;
typedef __attribute__((ext_vector_type(4))) _Float16 f16x4;
typedef __attribute__((ext_vector_type(4))) float f32x4;

__device__ __forceinline__ void gload16(const void* g, void* l) {
  __builtin_amdgcn_global_load_lds(
      (const __attribute__((address_space(1))) unsigned int*)g,
      (__attribute__((address_space(3))) unsigned int*)l, 16, 0, 0);
}

// gelu(v) = 0.5 v (1 + erf(v/sqrt2)), erf via Abramowitz-Stegun 7.1.26
__device__ __forceinline__ float gelu_fast(float v) {
  float az = fabsf(v) * 0.7071067811865476f;
  float t = __builtin_amdgcn_rcpf(fmaf(0.3275911f, az, 1.0f));
  float p = fmaf(fmaf(fmaf(fmaf(1.061405429f, t, -1.453152027f), t,
                           1.421413741f), t, -0.284496736f), t, 0.254829592f) * t;
  float e = __builtin_amdgcn_exp2f(az * az * -1.4426950408889634f);
  float erfa = fmaf(-p, e, 1.0f);
  float u = copysignf(erfa, v);
  return 0.5f * v * (1.0f + u);
}

// bijective XCD swizzle (nwg % 8 == 0 for all grids used here)
__device__ __forceinline__ int xcd_swz(int bid, int nwg) {
  return (bid & 7) * (nwg >> 3) + (bid >> 3);
}

// ---------------- small utility kernels ----------------

__global__ __launch_bounds__(256) void k_init(int* list, int* cnt) {
  int i = blockIdx.x * 256 + threadIdx.x;
  if (i < CAP) list[i] = -1;
  if (i < 4) cnt[i * CPAD] = 0;
}

// transpose-cast: in [E][R][Cc] f32 -> out [E][Cc][R] f16, 64x64 tiles
__global__ __launch_bounds__(256) void k_cast_t(const float* __restrict__ in,
                                                f16* __restrict__ out, int R, int Cc) {
  __shared__ f16 T[64][72];
  int ez = blockIdx.z;
  const float* ine = in + (size_t)ez * R * Cc;
  f16* oute = out + (size_t)ez * R * Cc;
  int c0 = blockIdx.x * 64;
  int r0 = blockIdx.y * 64;
  int t = threadIdx.x;
  {
    int rr = t >> 2, cc = (t & 3) * 16;
    const float* src = ine + (size_t)(r0 + rr) * Cc + c0 + cc;
    union { f16 h[16]; uint4 u[2]; } pk;
#pragma unroll
    for (int j = 0; j < 16; j += 4) {
      float4 a = *(const float4*)(src + j);
      pk.h[j] = (f16)a.x; pk.h[j + 1] = (f16)a.y;
      pk.h[j + 2] = (f16)a.z; pk.h[j + 3] = (f16)a.w;
    }
    *(uint4*)&T[rr][cc] = pk.u[0];
    *(uint4*)&T[rr][cc + 8] = pk.u[1];
  }
  __syncthreads();
  {
    int oc = t >> 2, orr = (t & 3) * 16;
    union { f16 h[16]; uint4 u[2]; } pk;
#pragma unroll
    for (int j = 0; j < 16; ++j) pk.h[j] = T[orr + j][oc];
    f16* dst = oute + (size_t)(c0 + oc) * R + r0 + orr;
    *(uint4*)dst = pk.u[0];
    *(uint4*)(dst + 8) = pk.u[1];
  }
}

// ---------------- router (fp32 exact) + fused x->fp16 cast ----------------

__global__ __launch_bounds__(256) void k_router(const float* __restrict__ x,
                                                const float* __restrict__ gw,
                                                f16* __restrict__ xh,
                                                float* __restrict__ rout,
                                                float4* __restrict__ tokinfo,
                                                int* __restrict__ cnt) {
  __shared__ int lcnt[4];
  int tid = threadIdx.x;
  if (tid < 4) lcnt[tid] = 0;
  __syncthreads();
  int wv = tid >> 6, lane = tid & 63;
  const float4* g = ((const float4*)gw) + lane * 8;
  float4 gv[8];
#pragma unroll
  for (int j = 0; j < 8; ++j) gv[j] = g[j];

  int tok0 = blockIdx.x * 64 + wv * 16;
  for (int i = 0; i < 16; ++i) {
    int tok = tok0 + i;
    const float4* xr = (const float4*)(x + (size_t)tok * CDIM + lane * 8);
    float4 a0 = xr[0], a1 = xr[1];
    union { f16 h[8]; uint4 u; } pk;
    pk.h[0] = (f16)a0.x; pk.h[1] = (f16)a0.y; pk.h[2] = (f16)a0.z; pk.h[3] = (f16)a0.w;
    pk.h[4] = (f16)a1.x; pk.h[5] = (f16)a1.y; pk.h[6] = (f16)a1.z; pk.h[7] = (f16)a1.w;
    *(uint4*)(xh + (size_t)tok * CDIM + lane * 8) = pk.u;
    float xv[8] = {a0.x, a0.y, a0.z, a0.w, a1.x, a1.y, a1.z, a1.w};
    float l0 = 0, l1 = 0, l2 = 0, l3 = 0;
#pragma unroll
    for (int j = 0; j < 8; ++j) {
      float4 g4 = gv[j];
      l0 = fmaf(xv[j], g4.x, l0); l1 = fmaf(xv[j], g4.y, l1);
      l2 = fmaf(xv[j], g4.z, l2); l3 = fmaf(xv[j], g4.w, l3);
    }
#pragma unroll
    for (int off = 32; off; off >>= 1) {
      l0 += __shfl_xor(l0, off); l1 += __shfl_xor(l1, off);
      l2 += __shfl_xor(l2, off); l3 += __shfl_xor(l3, off);
    }
    if (lane == 0) {
      float lg[4] = {l0, l1, l2, l3};
      float m = fmaxf(fmaxf(lg[0], lg[1]), fmaxf(lg[2], lg[3]));
      float p[4], s = 0.f;
#pragma unroll
      for (int e = 0; e < 4; ++e) { p[e] = expf(lg[e] - m); s += p[e]; }
      int i0 = 0;
#pragma unroll
      for (int e = 1; e < 4; ++e) if (lg[e] > lg[i0]) i0 = e;
      int i1 = -1;
#pragma unroll
      for (int e = 0; e < 4; ++e)
        if (e != i0 && (i1 < 0 || lg[e] > lg[i1])) i1 = e;
      float p0 = p[i0] / s, p1 = p[i1] / s;
      float ss = fmaxf(p0 + p1, 1e-6f);
      float w0 = p0 / ss, w1v = p1 / ss;
      float r[4] = {0.f, 0.f, 0.f, 0.f};
      r[i0] = w0; r[i1] = w1v;
      *(float4*)(rout + tok * 4) = make_float4(r[0], r[1], r[2], r[3]);
      float4 ti;
      ti.x = __int_as_float(i0); ti.y = __int_as_float(i1); ti.z = w0; ti.w = w1v;
      tokinfo[tok] = ti;
      atomicAdd(&lcnt[i0], 1);
      atomicAdd(&lcnt[i1], 1);
    }
  }
  __syncthreads();
  if (tid < 4) atomicAdd(cnt + tid * CPAD, lcnt[tid]);
}

__global__ void k_bases(const int* __restrict__ cnt, int* __restrict__ base,
                        int* __restrict__ cursor) {
  if (threadIdx.x == 0 && blockIdx.x == 0) {
    int b = 0;
#pragma unroll
    for (int e = 0; e < 4; ++e) {
      base[e] = b; cursor[e * CPAD] = b;
      b += (cnt[e * CPAD] + 127) & ~127;
    }
    base[4] = b;
  }
}

// slot assignment + inverse map (token -> its 2 slots)
__global__ __launch_bounds__(256) void k_assign(const float4* __restrict__ tokinfo,
                                                int* cursor, int* __restrict__ list,
                                                int2* __restrict__ tokslot) {
  __shared__ int lcnt[4], lbase[4];
  int tid = threadIdx.x;
  if (tid < 4) lcnt[tid] = 0;
  __syncthreads();
  int t0 = blockIdx.x * 1024 + tid * 4;
  float4 ti[4]; int lo0[4], lo1[4];
#pragma unroll
  for (int j = 0; j < 4; ++j) {
    ti[j] = tokinfo[t0 + j];
    lo0[j] = atomicAdd(&lcnt[__float_as_int(ti[j].x)], 1);
    lo1[j] = atomicAdd(&lcnt[__float_as_int(ti[j].y)], 1);
  }
  __syncthreads();
  if (tid < 4) lbase[tid] = atomicAdd(cursor + tid * CPAD, lcnt[tid]);
  __syncthreads();
#pragma unroll
  for (int j = 0; j < 4; ++j) {
    int s0 = lbase[__float_as_int(ti[j].x)] + lo0[j];
    list[s0] = t0 + j;
    int s1 = lbase[__float_as_int(ti[j].y)] + lo1[j];
    list[s1] = t0 + j;
    tokslot[t0 + j] = make_int2(s0, s1);
  }
}

// ---------------- pass 1: H[slot_local, 0..FF) = gelu(x[list] @ W1e) ----------------
// dbuf LDS (2x32KB), stage(k+1) issued BEFORE compute(k), one barrier/K-step.

__global__ __launch_bounds__(256) void k_gemm1(const f16* __restrict__ xh,
                                               const f16* __restrict__ w1t, // [E][FF][C]
                                               const int* __restrict__ list,
                                               const int* __restrict__ base,
                                               f16* __restrict__ H, int cb, int nwg) {
  __shared__ __align__(16) char smem[65536 + 512];
  int* slist = (int*)(smem + 65536);
  int tid = threadIdx.x;
  int wk = xcd_swz(blockIdx.x, nwg);
  int bx = wk >> 4, by = wk & 15;
  int m0 = (cb + bx) * BM;
  int mloc = bx * BM;
  int h0 = by * BN1;
  int e = 0;
#pragma unroll
  for (int i = 1; i < 4; ++i) if (m0 >= base[i]) e = i;
  if (tid < BM) {
    int v = list[m0 + tid];
    slist[tid] = v < 0 ? 0 : v;
  }
  __syncthreads();

  int tokr[4];
#pragma unroll
  for (int i = 0; i < 4; ++i) tokr[i] = slist[i * 32 + (tid >> 3)];

  const f16* wB = w1t + (size_t)(e * FF + h0) * CDIM;
  int kbs = ((tid & 7) * 16) ^ (((tid >> 3) & 7) << 4);

  f32x4 acc[4][4] = {};
  int lane = tid & 63, w = tid >> 6, wr = w >> 1, wc = w & 1;

  auto stage = [&](int kk, int p) {
    char* s = smem + p * 32768;
#pragma unroll
    for (int i = 0; i < 4; ++i) {   // A: gathered x rows
      gload16(xh + (size_t)tokr[i] * CDIM + kk * BK + (kbs >> 1),
              s + i * 4096 + tid * 16);
    }
#pragma unroll
    for (int i = 0; i < 4; ++i) {   // B: w1t rows (ff cols)
      int row = i * 32 + (tid >> 3);
      gload16(wB + (size_t)row * CDIM + kk * BK + (kbs >> 1),
              s + 16384 + i * 4096 + tid * 16);
    }
  };

  auto compute = [&](int p) {
    const char* s = smem + p * 32768;
#pragma unroll
    for (int ks = 0; ks < 2; ++ks) {
      f16x8 af[4], bfr[4];
      int kb = ks * 64 + (lane >> 4) * 16;
#pragma unroll
      for (int fr = 0; fr < 4; ++fr) {
        int row = wr * 64 + fr * 16 + (lane & 15);
        af[fr] = *(const f16x8*)(s + row * 128 + (kb ^ ((row & 7) << 4)));
      }
#pragma unroll
      for (int fc = 0; fc < 4; ++fc) {
        int col = wc * 64 + fc * 16 + (lane & 15);
        bfr[fc] = *(const f16x8*)(s + 16384 + col * 128 + (kb ^ ((col & 7) << 4)));
      }
#pragma unroll
      for (int fr = 0; fr < 4; ++fr)
#pragma unroll
        for (int fc = 0; fc < 4; ++fc)
          acc[fr][fc] = __builtin_amdgcn_mfma_f32_16x16x32_f16(af[fr], bfr[fc],
                                                               acc[fr][fc], 0, 0, 0);
    }
  };

  stage(0, 0);
  __syncthreads();                       // drain prologue stage
  for (int kk = 0; kk < 8; ++kk) {       // K = CDIM = 512
    if (kk < 7) stage(kk + 1, (kk + 1) & 1);
    __builtin_amdgcn_sched_barrier(0);   // keep load-issue ahead of compute
    __builtin_amdgcn_s_setprio(1);
    compute(kk & 1);
    __builtin_amdgcn_s_setprio(0);
    __syncthreads();                     // drains stage(kk+1); readers done
  }

  // epilogue: gelu -> fp16, LDS repack, coalesced 16B stores (H row stride FF)
#pragma unroll
  for (int fr = 0; fr < 4; ++fr)
#pragma unroll
    for (int fc = 0; fc < 4; ++fc)
#pragma unroll
      for (int i = 0; i < 4; ++i) {
        int row = wr * 64 + fr * 16 + (lane >> 4) * 4 + i;
        int col = wc * 64 + fc * 16 + (lane & 15);
        float v = gelu_fast(acc[fr][fc][i]);
        int off = (row * 256 + col * 2) ^ ((row & 7) << 4);
        *(f16*)(smem + off) = (f16)v;
      }
  __syncthreads();
#pragma unroll
  for (int j = 0; j < 8; ++j) {
    int row = j * 16 + (tid >> 4);
    int colb = ((tid & 15) * 16) ^ ((row & 7) << 4);
    uint4 v = *(const uint4*)(smem + row * 256 + colb);
    *(uint4*)((char*)H + ((size_t)(mloc + row) * FF + h0) * 2 + (tid & 15) * 16) = v;
  }
}

// ---------------- pass 2: Y[slot] = H[slot_local] @ W2e  (K = FF = 2048) ----------------
// dbuf LDS (2x24KB), same pipelined K-loop.

__global__ __launch_bounds__(256) void k_gemm2(const f16* __restrict__ H,
                                               const f16* __restrict__ w2t, // [E][C][FF]
                                               const int* __restrict__ base,
                                               f16* __restrict__ Y, int cb, int nwg) {
  __shared__ __align__(16) char smem[49152];
  int tid = threadIdx.x;
  int wk = xcd_swz(blockIdx.x, nwg);
  int bx = wk >> 3, by = wk & 7;
  int m0 = (cb + bx) * BM;
  int mloc = bx * BM;
  int c0 = by * BN2;
  int e = 0;
#pragma unroll
  for (int i = 1; i < 4; ++i) if (m0 >= base[i]) e = i;

  const f16* pA = H + (size_t)mloc * FF;
  const f16* wB = w2t + (size_t)(e * CDIM + c0) * FF;
  int kbs = ((tid & 7) * 16) ^ (((tid >> 3) & 7) << 4);

  f32x4 acc[4][2] = {};
  int lane = tid & 63, w = tid >> 6, wr = w >> 1, wc = w & 1;

  auto stage = [&](int kk, int p) {
    char* s = smem + p * 24576;
#pragma unroll
    for (int i = 0; i < 4; ++i) {   // A: H rows (local slots)
      int row = i * 32 + (tid >> 3);
      gload16(pA + (size_t)row * FF + kk * BK + (kbs >> 1),
              s + i * 4096 + tid * 16);
    }
#pragma unroll
    for (int i = 0; i < 2; ++i) {   // B: w2t rows (out cols), 8KB
      int row = i * 32 + (tid >> 3);
      gload16(wB + (size_t)row * FF + kk * BK + (kbs >> 1),
              s + 16384 + i * 4096 + tid * 16);
    }
  };

  auto compute = [&](int p) {
    const char* s = smem + p * 24576;
#pragma unroll
    for (int ks = 0; ks < 2; ++ks) {
      f16x8 af[4], bfr[2];
      int kb = ks * 64 + (lane >> 4) * 16;
#pragma unroll
      for (int fr = 0; fr < 4; ++fr) {
        int row = wr * 64 + fr * 16 + (lane & 15);
        af[fr] = *(const f16x8*)(s + row * 128 + (kb ^ ((row & 7) << 4)));
      }
#pragma unroll
      for (int fc = 0; fc < 2; ++fc) {
        int col = wc * 32 + fc * 16 + (lane & 15);
        bfr[fc] = *(const f16x8*)(s + 16384 + col * 128 + (kb ^ ((col & 7) << 4)));
      }
#pragma unroll
      for (int fr = 0; fr < 4; ++fr)
#pragma unroll
        for (int fc = 0; fc < 2; ++fc)
          acc[fr][fc] = __builtin_amdgcn_mfma_f32_16x16x32_f16(af[fr], bfr[fc],
                                                               acc[fr][fc], 0, 0, 0);
    }
  };

  stage(0, 0);
  __syncthreads();
  for (int kk = 0; kk < 32; ++kk) {      // K = FF = 2048
    if (kk < 31) stage(kk + 1, (kk + 1) & 1);
    __builtin_amdgcn_sched_barrier(0);
    __builtin_amdgcn_s_setprio(1);
    compute(kk & 1);
    __builtin_amdgcn_s_setprio(0);
    __syncthreads();
  }

  // epilogue: fp16 Y rows, LDS repack [128][64] f16, plain coalesced stores
#pragma unroll
  for (int fr = 0; fr < 4; ++fr)
#pragma unroll
    for (int fc = 0; fc < 2; ++fc)
#pragma unroll
      for (int i = 0; i < 4; ++i) {
        int row = wr * 64 + fr * 16 + (lane >> 4) * 4 + i;
        int col = wc * 32 + fc * 16 + (lane & 15);
        int off = (row * 128 + col * 2) ^ ((row & 7) << 4);
        *(f16*)(smem + off) = (f16)acc[fr][fc][i];
      }
  __syncthreads();
#pragma unroll
  for (int j = 0; j < 4; ++j) {
    int row = j * 32 + (tid >> 3);
    int colb = ((tid & 7) * 16) ^ ((row & 7) << 4);
    uint4 v = *(const uint4*)(smem + row * 128 + colb);
    *(uint4*)((char*)Y + ((size_t)(m0 + row) * CDIM + c0) * 2 + (tid & 7) * 16) = v;
  }
}

// ---------------- combine: out[tok] = w0*Y[s0] + w1*Y[s1] ----------------

__global__ __launch_bounds__(256) void k_combine(const f16* __restrict__ Y,
                                                 const float4* __restrict__ tokinfo,
                                                 const int2* __restrict__ tokslot,
                                                 float* __restrict__ out) {
  int gid = blockIdx.x * 256 + threadIdx.x;
  int tok = gid >> 7;
  int cc = (gid & 127) * 4;
  int2 sl = tokslot[tok];
  float4 ti = tokinfo[tok];
  f16x4 y0 = *(const f16x4*)(Y + (size_t)sl.x * CDIM + cc);
  f16x4 y1 = *(const f16x4*)(Y + (size_t)sl.y * CDIM + cc);
  float w0 = ti.z, w1 = ti.w;
  float4 o;
  o.x = w0 * (float)y0[0] + w1 * (float)y1[0];
  o.y = w0 * (float)y0[1] + w1 * (float)y1[1];
  o.z = w0 * (float)y0[2] + w1 * (float)y1[2];
  o.w = w0 * (float)y0[3] + w1 * (float)y1[3];
  *(float4*)(out + (size_t)tok * CDIM + cc) = o;
}

// ---------------- host ----------------

extern "C" void kernel_launch(void* const* d_in, const int* in_sizes, int n_in,
                              void* d_out, int out_size, void* d_ws, size_t ws_size,
                              hipStream_t stream) {
  const float* x  = (const float*)d_in[0];
  const float* gw = (const float*)d_in[1];
  const float* w1 = (const float*)d_in[2];
  const float* w2 = (const float*)d_in[3];
  float* out  = (float*)d_out;
  float* rout = out + (size_t)NTOK * CDIM;

  char* ws = (char*)d_ws;
  f16* xh      = (f16*)ws;      ws += (size_t)NTOK * CDIM * 2;       // 16.78 MB
  f16* w1t     = (f16*)ws;      ws += (size_t)NEXP * FF * CDIM * 2;  //  8.39 MB
  f16* w2t     = (f16*)ws;      ws += (size_t)NEXP * FF * CDIM * 2;  //  8.39 MB
  f16* Ybuf    = (f16*)ws;      ws += (size_t)CAP * CDIM * 2;        // 34.08 MB
  float4* tokinfo = (float4*)ws; ws += (size_t)NTOK * 16;            //  0.26 MB
  int2* tokslot = (int2*)ws;    ws += (size_t)NTOK * 8;              //  0.13 MB
  int* list    = (int*)ws;      ws += (size_t)CAP * 4;               //  0.13 MB
  int* cnt     = (int*)ws;      ws += 4 * CPAD * 4;
  int* base    = (int*)ws;      ws += 64;
  int* cursor  = (int*)ws;      ws += 4 * CPAD * 4;
  f16* Hbuf    = (f16*)ws;      // CB*128*FF fp16, sized by ladder below

  size_t base_bytes = (size_t)(ws - (char*)d_ws);
  const int opts[12] = {260, 130, 65, 52, 26, 20, 13, 10, 5, 4, 2, 1};
  int CB = 1;
  for (int oi = 0; oi < 12; ++oi) {
    if (base_bytes + (size_t)opts[oi] * BM * FF * 2 <= ws_size) { CB = opts[oi]; break; }
  }

  k_init<<<(CAP + 255) / 256, 256, 0, stream>>>(list, cnt);
  k_cast_t<<<dim3(FF / 64, CDIM / 64, NEXP), 256, 0, stream>>>(w1, w1t, CDIM, FF);
  k_cast_t<<<dim3(CDIM / 64, FF / 64, NEXP), 256, 0, stream>>>(w2, w2t, FF, CDIM);
  k_router<<<NTOK / 64, 256, 0, stream>>>(x, gw, xh, rout, tokinfo, cnt);
  k_bases<<<1, 64, 0, stream>>>(cnt, base, cursor);
  k_assign<<<NTOK / 1024, 256, 0, stream>>>(tokinfo, cursor, list, tokslot);

  for (int cb = 0; cb < NBLK; cb += CB) {
    int n1 = CB * 16, n2 = CB * 8;
    k_gemm1<<<n1, 256, 0, stream>>>(xh, w1t, list, base, Hbuf, cb, n1);
    k_gemm2<<<n2, 256, 0, stream>>>(Hbuf, w2t, base, Ybuf, cb, n2);
  }
  k_combine<<<NTOK * CDIM / 4 / 256, 256, 0, stream>>>(Ybuf, tokinfo, tokslot, out);
}